// Round 1
// baseline (629.888 us; speedup 1.0000x reference)
//
#include <hip/hip_runtime.h>

// GCN on MI355X.
// Inputs (fp32 unless noted): x[N,128], edge_index[2,E] (int), W1[128,64], b1[64],
//                             W2[64,32], b2[32], Wl[32,1], bl[1]
// Output: [N,1] fp32.
//
// Algebra: layer2 collapses through the linear head:
//   out = segsum(((relu(c1)*ns) @ W2)[src], dst)*nd @ Wl + b2@Wl + bl
//       = segsum((relu(c1) . (W2@Wl) * ns)[src], dst)*nd + (b2@Wl + bl)
// so only a per-node SCALAR is scattered for layer 2.

#define WAVE 64

__device__ __forceinline__ void f32_atomic_add(float* p, float v) {
    // native global_atomic_add_f32 (avoid CAS loop that plain atomicAdd may emit)
    unsafeAtomicAdd(p, v);
}

__global__ __launch_bounds__(256) void k_degree(const int* __restrict__ src,
                                                const int* __restrict__ dst,
                                                unsigned* __restrict__ cs,
                                                unsigned* __restrict__ cd, int E) {
    int i = blockIdx.x * 256 + threadIdx.x;
    if (i < E) {
        atomicAdd(&cs[src[i]], 1u);
        atomicAdd(&cd[dst[i]], 1u);
    }
}

// counts (uint) -> inverse-sqrt norm (float), in place
__global__ __launch_bounds__(256) void k_norm(unsigned* __restrict__ cs,
                                              unsigned* __restrict__ cd, int N) {
    int i = blockIdx.x * 256 + threadIdx.x;
    if (i < N) {
        unsigned a = cs[i], b = cd[i];
        float na = a ? rsqrtf((float)a) : 0.0f;
        float nb = b ? rsqrtf((float)b) : 0.0f;
        ((float*)cs)[i] = na;
        ((float*)cd)[i] = nb;
    }
}

// w2l[c] = sum_j W2[c][j]*Wl[j]; c0 = b2.Wl + bl
__global__ void k_w2l(const float* __restrict__ W2, const float* __restrict__ b2,
                      const float* __restrict__ Wl, const float* __restrict__ bl,
                      float* __restrict__ w2l, float* __restrict__ c0) {
    int c = threadIdx.x; // 64 threads
    float acc = 0.f;
#pragma unroll
    for (int j = 0; j < 32; ++j) acc += W2[c * 32 + j] * Wl[j];
    w2l[c] = acc;
    if (c == 0) {
        float s = 0.f;
#pragma unroll
        for (int j = 0; j < 32; ++j) s += b2[j] * Wl[j];
        *c0 = s + bl[0];
    }
}

// h1 = (x * norm_src[:,None]) @ W1    [N,128]@[128,64]
// block=256, tile 64 rows x 64 cols, K tiled by 64. Row-scale applied at store
// (diag(norm) commutes through the GEMM).
__global__ __launch_bounds__(256) void k_gemm1(const float* __restrict__ x,
                                               const float* __restrict__ W1,
                                               const float* __restrict__ norm_s,
                                               float* __restrict__ h1, int N) {
    __shared__ float xT[64][65];                 // [k][r], pad -> conflict-free writes
    __shared__ __align__(16) float Ws[64][64];   // [k][c]
    const int tid = threadIdx.x;
    const int tx = tid & 15;   // col group: cols 4*tx..4*tx+3
    const int ty = tid >> 4;   // row group: rows 4*ty..4*ty+3
    const int r0 = blockIdx.x * 64;

    float acc[4][4] = {};

#pragma unroll
    for (int kt = 0; kt < 2; ++kt) {
        // stage x tile (transposed) and W tile
#pragma unroll
        for (int it = 0; it < 16; ++it) {
            int e = it * 256 + tid;
            int r = e >> 6, k = e & 63;
            int row = r0 + r;
            float v = 0.f;
            if (row < N) v = x[(size_t)row * 128 + kt * 64 + k];
            xT[k][r] = v;
        }
#pragma unroll
        for (int it = 0; it < 16; ++it) {
            int e = it * 256 + tid;
            int k = e >> 6, c = e & 63;
            Ws[k][c] = W1[(size_t)(kt * 64 + k) * 64 + c];
        }
        __syncthreads();
#pragma unroll 8
        for (int k = 0; k < 64; ++k) {
            float4 wv = *(const float4*)&Ws[k][tx * 4];
            float x0 = xT[k][ty * 4 + 0];
            float x1 = xT[k][ty * 4 + 1];
            float x2 = xT[k][ty * 4 + 2];
            float x3 = xT[k][ty * 4 + 3];
            acc[0][0] = fmaf(x0, wv.x, acc[0][0]); acc[0][1] = fmaf(x0, wv.y, acc[0][1]);
            acc[0][2] = fmaf(x0, wv.z, acc[0][2]); acc[0][3] = fmaf(x0, wv.w, acc[0][3]);
            acc[1][0] = fmaf(x1, wv.x, acc[1][0]); acc[1][1] = fmaf(x1, wv.y, acc[1][1]);
            acc[1][2] = fmaf(x1, wv.z, acc[1][2]); acc[1][3] = fmaf(x1, wv.w, acc[1][3]);
            acc[2][0] = fmaf(x2, wv.x, acc[2][0]); acc[2][1] = fmaf(x2, wv.y, acc[2][1]);
            acc[2][2] = fmaf(x2, wv.z, acc[2][2]); acc[2][3] = fmaf(x2, wv.w, acc[2][3]);
            acc[3][0] = fmaf(x3, wv.x, acc[3][0]); acc[3][1] = fmaf(x3, wv.y, acc[3][1]);
            acc[3][2] = fmaf(x3, wv.z, acc[3][2]); acc[3][3] = fmaf(x3, wv.w, acc[3][3]);
        }
        __syncthreads();
    }

#pragma unroll
    for (int i = 0; i < 4; ++i) {
        int row = r0 + ty * 4 + i;
        if (row < N) {
            float ns = norm_s[row];
            float4 o = make_float4(acc[i][0] * ns, acc[i][1] * ns,
                                   acc[i][2] * ns, acc[i][3] * ns);
            *(float4*)&h1[(size_t)row * 64 + tx * 4] = o;
        }
    }
}

// agg[dst] += h1[src], 64 channels wide. One wave handles 64 edges per chunk:
// lane loads its own (src,dst) pair, then the wave iterates the 64 edges via
// shfl broadcast; lane == channel -> coalesced 256B gather + 64 atomics/edge.
__global__ __launch_bounds__(256) void k_scatter64(const int* __restrict__ src,
                                                   const int* __restrict__ dst,
                                                   const float* __restrict__ h1,
                                                   float* __restrict__ agg, int E) {
    const int lane = threadIdx.x & 63;
    const int wid = (blockIdx.x * 256 + threadIdx.x) >> 6;
    const int nw = (gridDim.x * 256) >> 6;
    for (int base = wid * WAVE; base < E; base += nw * WAVE) {
        int ns = min(WAVE, E - base);
        int sv = 0, dv = 0;
        if (lane < ns) { sv = src[base + lane]; dv = dst[base + lane]; }
        for (int i = 0; i < ns; ++i) {
            int s = __shfl(sv, i);
            int d = __shfl(dv, i);
            float v = h1[(size_t)s * 64 + lane];
            f32_atomic_add(&agg[(size_t)d * 64 + lane], v);
        }
    }
}

// s_node[v] = (relu(agg[v]*nd[v] + b1) . w2l) * ns[v]   — one wave per node
__global__ __launch_bounds__(256) void k_rdot(const float* __restrict__ agg,
                                              const float* __restrict__ norm_s,
                                              const float* __restrict__ norm_d,
                                              const float* __restrict__ b1,
                                              const float* __restrict__ w2l,
                                              float* __restrict__ s_node, int N) {
    const int lane = threadIdx.x & 63;
    const int v = (blockIdx.x * 256 + threadIdx.x) >> 6;
    if (v >= N) return;
    float t = fmaf(agg[(size_t)v * 64 + lane], norm_d[v], b1[lane]);
    t = fmaxf(t, 0.f) * w2l[lane];
#pragma unroll
    for (int off = 32; off; off >>= 1) t += __shfl_xor(t, off);
    if (lane == 0) s_node[v] = t * norm_s[v];
}

__global__ __launch_bounds__(256) void k_scatter1(const int* __restrict__ src,
                                                  const int* __restrict__ dst,
                                                  const float* __restrict__ s_node,
                                                  float* __restrict__ out, int E) {
    int i = blockIdx.x * 256 + threadIdx.x;
    if (i < E) f32_atomic_add(&out[dst[i]], s_node[src[i]]);
}

__global__ __launch_bounds__(256) void k_final(float* __restrict__ out,
                                               const float* __restrict__ norm_d,
                                               const float* __restrict__ c0, int N) {
    int i = blockIdx.x * 256 + threadIdx.x;
    if (i < N) out[i] = fmaf(out[i], norm_d[i], *c0);
}

extern "C" void kernel_launch(void* const* d_in, const int* in_sizes, int n_in,
                              void* d_out, int out_size, void* d_ws, size_t ws_size,
                              hipStream_t stream) {
    const float* x  = (const float*)d_in[0];
    const int*   ei = (const int*)d_in[1];   // harness delivers integer inputs as int32
    const float* W1 = (const float*)d_in[2];
    const float* b1 = (const float*)d_in[3];
    const float* W2 = (const float*)d_in[4];
    const float* b2 = (const float*)d_in[5];
    const float* Wl = (const float*)d_in[6];
    const float* bl = (const float*)d_in[7];

    const int N = in_sizes[0] / 128;
    const int E = in_sizes[1] / 2;
    const int* src = ei;
    const int* dst = ei + E;

    char* w = (char*)d_ws;
    auto alloc = [&](size_t bytes) -> void* {
        void* r = (void*)w;
        w += (bytes + 255) & ~(size_t)255;
        return r;
    };
    unsigned* cs     = (unsigned*)alloc((size_t)N * 4);        // counts -> norm_src
    unsigned* cd     = (unsigned*)alloc((size_t)N * 4);        // counts -> norm_dst
    float*    h1     = (float*)alloc((size_t)N * 64 * 4);
    float*    agg    = (float*)alloc((size_t)N * 64 * 4);
    float*    s_node = (float*)alloc((size_t)N * 4);
    float*    w2l    = (float*)alloc(64 * 4);
    float*    c0     = (float*)alloc(4);

    float* out = (float*)d_out;

    hipMemsetAsync(cs, 0, (size_t)N * 4, stream);
    hipMemsetAsync(cd, 0, (size_t)N * 4, stream);
    hipMemsetAsync(agg, 0, (size_t)N * 64 * 4, stream);
    hipMemsetAsync(out, 0, (size_t)N * 4, stream);

    k_degree<<<(E + 255) / 256, 256, 0, stream>>>(src, dst, cs, cd, E);
    k_w2l<<<1, 64, 0, stream>>>(W2, b2, Wl, bl, w2l, c0);
    k_norm<<<(N + 255) / 256, 256, 0, stream>>>(cs, cd, N);
    k_gemm1<<<(N + 63) / 64, 256, 0, stream>>>(x, W1, (const float*)cs, h1, N);

    int chunks = (E + 63) / 64;                 // one wave per 64-edge chunk
    k_scatter64<<<(chunks + 3) / 4, 256, 0, stream>>>(src, dst, h1, agg, E);

    k_rdot<<<(N + 3) / 4, 256, 0, stream>>>(agg, (const float*)cs, (const float*)cd,
                                            b1, w2l, s_node, N);
    k_scatter1<<<(E + 255) / 256, 256, 0, stream>>>(src, dst, s_node, out, E);
    k_final<<<(N + 255) / 256, 256, 0, stream>>>(out, (const float*)cd, c0, N);
}

// Round 2
// 387.947 us; speedup vs baseline: 1.6236x; 1.6236x over previous
//
#include <hip/hip_runtime.h>

// GCN on MI355X — CSR-based aggregation (no fp atomics).
//
// Algebra: layer2 collapses through the linear head:
//   out = segsum((relu(c1) . (W2@Wl) * ns)[src], dst)*nd + (b2@Wl + bl)
// so only a per-node SCALAR feeds the second aggregation.
//
// Pipeline:
//   deg counts -> norms; exclusive scan(deg_d) -> CSR offsets; fill CSR (int atomics)
//   gemm1: h1 = (x*ns) @ W1
//   k_agg_rdot: per-node register aggregation of h1[src] over in-edges (one wave/node),
//               fused with relu/norm/dot(w2l) -> s_node   (agg never materialized)
//   k_out: per-node CSR sum of s_node[src] -> out

#define WAVE 64

__global__ __launch_bounds__(256) void k_degree(const int* __restrict__ src,
                                                const int* __restrict__ dst,
                                                unsigned* __restrict__ deg_s,
                                                unsigned* __restrict__ deg_d, int E) {
    int i = blockIdx.x * 256 + threadIdx.x;
    if (i < E) {
        atomicAdd(&deg_s[src[i]], 1u);
        atomicAdd(&deg_d[dst[i]], 1u);
    }
}

__global__ __launch_bounds__(256) void k_norm(const unsigned* __restrict__ deg_s,
                                              const unsigned* __restrict__ deg_d,
                                              float* __restrict__ norm_s,
                                              float* __restrict__ norm_d, int N) {
    int i = blockIdx.x * 256 + threadIdx.x;
    if (i < N) {
        unsigned a = deg_s[i], b = deg_d[i];
        norm_s[i] = a ? rsqrtf((float)a) : 0.0f;
        norm_d[i] = b ? rsqrtf((float)b) : 0.0f;
    }
}

// w2l[c] = sum_j W2[c][j]*Wl[j]; c0 = b2.Wl + bl
__global__ void k_w2l(const float* __restrict__ W2, const float* __restrict__ b2,
                      const float* __restrict__ Wl, const float* __restrict__ bl,
                      float* __restrict__ w2l, float* __restrict__ c0) {
    int c = threadIdx.x; // 64 threads
    float acc = 0.f;
#pragma unroll
    for (int j = 0; j < 32; ++j) acc += W2[c * 32 + j] * Wl[j];
    w2l[c] = acc;
    if (c == 0) {
        float s = 0.f;
#pragma unroll
        for (int j = 0; j < 32; ++j) s += b2[j] * Wl[j];
        *c0 = s + bl[0];
    }
}

// ---- scan: deg_d -> exclusive offsets (N+1) ----
__global__ __launch_bounds__(256) void k_blocksum(const unsigned* __restrict__ deg,
                                                  unsigned* __restrict__ partial, int N) {
    __shared__ unsigned sw[4];
    int i = blockIdx.x * 256 + threadIdx.x;
    unsigned v = (i < N) ? deg[i] : 0u;
#pragma unroll
    for (int off = 32; off; off >>= 1) v += __shfl_xor((int)v, off);
    if ((threadIdx.x & 63) == 0) sw[threadIdx.x >> 6] = v;
    __syncthreads();
    if (threadIdx.x == 0) partial[blockIdx.x] = sw[0] + sw[1] + sw[2] + sw[3];
}

// single block, 512 threads: exclusive scan of `partial[0..nb)`; offsets[N] = total
__global__ __launch_bounds__(512) void k_scanpartial(const unsigned* __restrict__ partial,
                                                     unsigned* __restrict__ blockoff,
                                                     unsigned* __restrict__ offsets,
                                                     int nb, int N) {
    __shared__ unsigned s[512];
    int t = threadIdx.x;
    unsigned v = (t < nb) ? partial[t] : 0u;
    s[t] = v;
    __syncthreads();
    for (int off = 1; off < 512; off <<= 1) {
        unsigned a = (t >= off) ? s[t - off] : 0u;
        __syncthreads();
        s[t] += a;
        __syncthreads();
    }
    if (t < nb) blockoff[t] = s[t] - v;       // exclusive
    if (t == nb - 1) offsets[N] = s[t];       // total = E
}

__global__ __launch_bounds__(256) void k_offsets(const unsigned* __restrict__ deg,
                                                 const unsigned* __restrict__ blockoff,
                                                 unsigned* __restrict__ offsets,
                                                 unsigned* __restrict__ cursor, int N) {
    __shared__ unsigned s[256];
    int t = threadIdx.x;
    int i = blockIdx.x * 256 + t;
    unsigned v = (i < N) ? deg[i] : 0u;
    s[t] = v;
    __syncthreads();
    for (int off = 1; off < 256; off <<= 1) {
        unsigned a = (t >= off) ? s[t - off] : 0u;
        __syncthreads();
        s[t] += a;
        __syncthreads();
    }
    if (i < N) {
        unsigned o = blockoff[blockIdx.x] + s[t] - v;
        offsets[i] = o;
        cursor[i] = o;
    }
}

__global__ __launch_bounds__(256) void k_fill(const int* __restrict__ src,
                                              const int* __restrict__ dst,
                                              unsigned* __restrict__ cursor,
                                              unsigned* __restrict__ csr, int E) {
    int i = blockIdx.x * 256 + threadIdx.x;
    if (i < E) {
        int d = dst[i];
        unsigned pos = atomicAdd(&cursor[d], 1u);
        csr[pos] = (unsigned)src[i];
    }
}

// h1 = (x * norm_src[:,None]) @ W1    [N,128]@[128,64]
__global__ __launch_bounds__(256) void k_gemm1(const float* __restrict__ x,
                                               const float* __restrict__ W1,
                                               const float* __restrict__ norm_s,
                                               float* __restrict__ h1, int N) {
    __shared__ float xT[64][65];
    __shared__ __align__(16) float Ws[64][64];
    const int tid = threadIdx.x;
    const int tx = tid & 15;
    const int ty = tid >> 4;
    const int r0 = blockIdx.x * 64;

    float acc[4][4] = {};

#pragma unroll
    for (int kt = 0; kt < 2; ++kt) {
#pragma unroll
        for (int it = 0; it < 16; ++it) {
            int e = it * 256 + tid;
            int r = e >> 6, k = e & 63;
            int row = r0 + r;
            float v = 0.f;
            if (row < N) v = x[(size_t)row * 128 + kt * 64 + k];
            xT[k][r] = v;
        }
#pragma unroll
        for (int it = 0; it < 16; ++it) {
            int e = it * 256 + tid;
            int k = e >> 6, c = e & 63;
            Ws[k][c] = W1[(size_t)(kt * 64 + k) * 64 + c];
        }
        __syncthreads();
#pragma unroll 8
        for (int k = 0; k < 64; ++k) {
            float4 wv = *(const float4*)&Ws[k][tx * 4];
            float x0 = xT[k][ty * 4 + 0];
            float x1 = xT[k][ty * 4 + 1];
            float x2 = xT[k][ty * 4 + 2];
            float x3 = xT[k][ty * 4 + 3];
            acc[0][0] = fmaf(x0, wv.x, acc[0][0]); acc[0][1] = fmaf(x0, wv.y, acc[0][1]);
            acc[0][2] = fmaf(x0, wv.z, acc[0][2]); acc[0][3] = fmaf(x0, wv.w, acc[0][3]);
            acc[1][0] = fmaf(x1, wv.x, acc[1][0]); acc[1][1] = fmaf(x1, wv.y, acc[1][1]);
            acc[1][2] = fmaf(x1, wv.z, acc[1][2]); acc[1][3] = fmaf(x1, wv.w, acc[1][3]);
            acc[2][0] = fmaf(x2, wv.x, acc[2][0]); acc[2][1] = fmaf(x2, wv.y, acc[2][1]);
            acc[2][2] = fmaf(x2, wv.z, acc[2][2]); acc[2][3] = fmaf(x2, wv.w, acc[2][3]);
            acc[3][0] = fmaf(x3, wv.x, acc[3][0]); acc[3][1] = fmaf(x3, wv.y, acc[3][1]);
            acc[3][2] = fmaf(x3, wv.z, acc[3][2]); acc[3][3] = fmaf(x3, wv.w, acc[3][3]);
        }
        __syncthreads();
    }

#pragma unroll
    for (int i = 0; i < 4; ++i) {
        int row = r0 + ty * 4 + i;
        if (row < N) {
            float ns = norm_s[row];
            float4 o = make_float4(acc[i][0] * ns, acc[i][1] * ns,
                                   acc[i][2] * ns, acc[i][3] * ns);
            *(float4*)&h1[(size_t)row * 64 + tx * 4] = o;
        }
    }
}

// One wave per node: register-accumulate h1[src] over in-edges, then fused
// relu/norm/dot(w2l) -> s_node.  lane == channel -> each edge is one coalesced
// 256B read from the LLC-resident h1.
__global__ __launch_bounds__(256) void k_agg_rdot(const unsigned* __restrict__ offsets,
                                                  const unsigned* __restrict__ csr,
                                                  const float* __restrict__ h1,
                                                  const float* __restrict__ norm_s,
                                                  const float* __restrict__ norm_d,
                                                  const float* __restrict__ b1,
                                                  const float* __restrict__ w2l,
                                                  float* __restrict__ s_node, int N) {
    const int lane = threadIdx.x & 63;
    const int v = (blockIdx.x * 256 + threadIdx.x) >> 6;
    if (v >= N) return;
    const unsigned beg = offsets[v], end = offsets[v + 1];
    float acc = 0.f;
    for (unsigned base = beg; base < end; base += WAVE) {
        const int n = (int)min((unsigned)WAVE, end - base);
        int sv = (lane < n) ? (int)csr[base + lane] : 0;
        int i = 0;
        for (; i + 4 <= n; i += 4) {  // 4 independent loads in flight
            int s0 = __shfl(sv, i + 0), s1 = __shfl(sv, i + 1);
            int s2 = __shfl(sv, i + 2), s3 = __shfl(sv, i + 3);
            float v0 = h1[(size_t)s0 * 64 + lane];
            float v1 = h1[(size_t)s1 * 64 + lane];
            float v2 = h1[(size_t)s2 * 64 + lane];
            float v3 = h1[(size_t)s3 * 64 + lane];
            acc += v0 + v1 + v2 + v3;
        }
        for (; i < n; ++i) {
            int s = __shfl(sv, i);
            acc += h1[(size_t)s * 64 + lane];
        }
    }
    float t = fmaf(acc, norm_d[v], b1[lane]);
    t = fmaxf(t, 0.f) * w2l[lane];
#pragma unroll
    for (int off = 32; off; off >>= 1) t += __shfl_xor(t, off);
    if (lane == 0) s_node[v] = t * norm_s[v];
}

// out[v] = nd[v] * sum_{in-edges} s_node[src] + c0
__global__ __launch_bounds__(256) void k_out(const unsigned* __restrict__ offsets,
                                             const unsigned* __restrict__ csr,
                                             const float* __restrict__ s_node,
                                             const float* __restrict__ norm_d,
                                             const float* __restrict__ c0,
                                             float* __restrict__ out, int N) {
    int v = blockIdx.x * 256 + threadIdx.x;
    if (v >= N) return;
    unsigned beg = offsets[v], end = offsets[v + 1];
    float sum = 0.f;
    unsigned j = beg;
    for (; j + 4 <= end; j += 4) {
        float a = s_node[csr[j + 0]], b = s_node[csr[j + 1]];
        float c = s_node[csr[j + 2]], d = s_node[csr[j + 3]];
        sum += a + b + c + d;
    }
    for (; j < end; ++j) sum += s_node[csr[j]];
    out[v] = fmaf(sum, norm_d[v], *c0);
}

extern "C" void kernel_launch(void* const* d_in, const int* in_sizes, int n_in,
                              void* d_out, int out_size, void* d_ws, size_t ws_size,
                              hipStream_t stream) {
    const float* x  = (const float*)d_in[0];
    const int*   ei = (const int*)d_in[1];
    const float* W1 = (const float*)d_in[2];
    const float* b1 = (const float*)d_in[3];
    const float* W2 = (const float*)d_in[4];
    const float* b2 = (const float*)d_in[5];
    const float* Wl = (const float*)d_in[6];
    const float* bl = (const float*)d_in[7];

    const int N = in_sizes[0] / 128;
    const int E = in_sizes[1] / 2;
    const int* src = ei;
    const int* dst = ei + E;
    const int NB = (N + 255) / 256;

    char* w = (char*)d_ws;
    auto alloc = [&](size_t bytes) -> void* {
        void* r = (void*)w;
        w += (bytes + 255) & ~(size_t)255;
        return r;
    };
    unsigned* deg_s   = (unsigned*)alloc((size_t)N * 4);
    unsigned* deg_d   = (unsigned*)alloc((size_t)N * 4);
    float*    norm_s  = (float*)alloc((size_t)N * 4);
    float*    norm_d  = (float*)alloc((size_t)N * 4);
    unsigned* offsets = (unsigned*)alloc((size_t)(N + 1) * 4);
    unsigned* cursor  = (unsigned*)alloc((size_t)N * 4);
    unsigned* partial = (unsigned*)alloc((size_t)NB * 4);
    unsigned* blockoff= (unsigned*)alloc((size_t)NB * 4);
    float*    h1      = (float*)alloc((size_t)N * 64 * 4);
    unsigned* csr     = (unsigned*)alloc((size_t)E * 4);
    float*    s_node  = (float*)alloc((size_t)N * 4);
    float*    w2l     = (float*)alloc(64 * 4);
    float*    c0      = (float*)alloc(4);

    float* out = (float*)d_out;

    hipMemsetAsync(deg_s, 0, (size_t)N * 4, stream);
    hipMemsetAsync(deg_d, 0, (size_t)N * 4, stream);

    k_degree<<<(E + 255) / 256, 256, 0, stream>>>(src, dst, deg_s, deg_d, E);
    k_w2l<<<1, 64, 0, stream>>>(W2, b2, Wl, bl, w2l, c0);
    k_norm<<<NB, 256, 0, stream>>>(deg_s, deg_d, norm_s, norm_d, N);

    k_blocksum<<<NB, 256, 0, stream>>>(deg_d, partial, N);
    k_scanpartial<<<1, 512, 0, stream>>>(partial, blockoff, offsets, NB, N);
    k_offsets<<<NB, 256, 0, stream>>>(deg_d, blockoff, offsets, cursor, N);
    k_fill<<<(E + 255) / 256, 256, 0, stream>>>(src, dst, cursor, csr, E);

    k_gemm1<<<(N + 63) / 64, 256, 0, stream>>>(x, W1, norm_s, h1, N);

    k_agg_rdot<<<(N + 3) / 4, 256, 0, stream>>>(offsets, csr, h1, norm_s, norm_d,
                                                b1, w2l, s_node, N);
    k_out<<<NB, 256, 0, stream>>>(offsets, csr, s_node, norm_d, c0, out, N);
}

// Round 3
// 332.759 us; speedup vs baseline: 1.8929x; 1.1658x over previous
//
#include <hip/hip_runtime.h>

// GCN on MI355X — CSR aggregation with XCD-partitioned CSR build.
//
// Algebra: layer2 collapses through the linear head:
//   out = segsum((relu(c1) . (W2@Wl) * ns)[src], dst)*nd + (b2@Wl + bl)
// so only a per-node SCALAR feeds the second aggregation.
//
// R2 change: k_degree/k_fill random 4B stores+atomics were writing 106MB to HBM
// (every 4B store = 64B sector flush, lines shared across XCDs never coalesce).
// Now: dst-space split into 8 ranges; block r=blockIdx&7 handles only range r
// (default round-robin dispatch => range r stays on one XCD => its L2 coalesces
// the writes). Edge list is re-read 8x but coalesced (~102MB @ BW ~= 16us).

#define WAVE 64
#define NRANGE 8
#define NCHUNK 256

// Partitioned degree count: deg_s filtered by src-range, deg_d by dst-range.
__global__ __launch_bounds__(256) void k_count(const int* __restrict__ src,
                                               const int* __restrict__ dst,
                                               unsigned* __restrict__ deg_s,
                                               unsigned* __restrict__ deg_d,
                                               int E, int step, int chunkE) {
    const int r = blockIdx.x & (NRANGE - 1);
    const int c = blockIdx.x / NRANGE;
    const int lo = r * step, hi = lo + step;
    const int beg = c * chunkE;
    const int end = min(beg + chunkE, E);
    for (int i = beg + threadIdx.x; i < end; i += 256) {
        int s = src[i];
        if (s >= lo && s < hi) atomicAdd(&deg_s[s], 1u);
        int d = dst[i];
        if (d >= lo && d < hi) atomicAdd(&deg_d[d], 1u);
    }
}

// Partitioned CSR fill (by dst range).
__global__ __launch_bounds__(256) void k_fill(const int* __restrict__ src,
                                              const int* __restrict__ dst,
                                              unsigned* __restrict__ cursor,
                                              unsigned* __restrict__ csr,
                                              int E, int step, int chunkE) {
    const int r = blockIdx.x & (NRANGE - 1);
    const int c = blockIdx.x / NRANGE;
    const int lo = r * step, hi = lo + step;
    const int beg = c * chunkE;
    const int end = min(beg + chunkE, E);
    for (int i = beg + threadIdx.x; i < end; i += 256) {
        int d = dst[i];
        if (d >= lo && d < hi) {
            unsigned pos = atomicAdd(&cursor[d], 1u);
            csr[pos] = (unsigned)src[i];
        }
    }
}

__global__ __launch_bounds__(256) void k_norm(const unsigned* __restrict__ deg_s,
                                              const unsigned* __restrict__ deg_d,
                                              float* __restrict__ norm_s,
                                              float* __restrict__ norm_d, int N) {
    int i = blockIdx.x * 256 + threadIdx.x;
    if (i < N) {
        unsigned a = deg_s[i], b = deg_d[i];
        norm_s[i] = a ? rsqrtf((float)a) : 0.0f;
        norm_d[i] = b ? rsqrtf((float)b) : 0.0f;
    }
}

// w2l[c] = sum_j W2[c][j]*Wl[j]; c0 = b2.Wl + bl
__global__ void k_w2l(const float* __restrict__ W2, const float* __restrict__ b2,
                      const float* __restrict__ Wl, const float* __restrict__ bl,
                      float* __restrict__ w2l, float* __restrict__ c0) {
    int c = threadIdx.x; // 64 threads
    float acc = 0.f;
#pragma unroll
    for (int j = 0; j < 32; ++j) acc += W2[c * 32 + j] * Wl[j];
    w2l[c] = acc;
    if (c == 0) {
        float s = 0.f;
#pragma unroll
        for (int j = 0; j < 32; ++j) s += b2[j] * Wl[j];
        *c0 = s + bl[0];
    }
}

// ---- scan: deg_d -> exclusive offsets (N+1) ----
__global__ __launch_bounds__(256) void k_blocksum(const unsigned* __restrict__ deg,
                                                  unsigned* __restrict__ partial, int N) {
    __shared__ unsigned sw[4];
    int i = blockIdx.x * 256 + threadIdx.x;
    unsigned v = (i < N) ? deg[i] : 0u;
#pragma unroll
    for (int off = 32; off; off >>= 1) v += __shfl_xor((int)v, off);
    if ((threadIdx.x & 63) == 0) sw[threadIdx.x >> 6] = v;
    __syncthreads();
    if (threadIdx.x == 0) partial[blockIdx.x] = sw[0] + sw[1] + sw[2] + sw[3];
}

// single block, 512 threads: exclusive scan of partial[0..nb); offsets[N] = total
__global__ __launch_bounds__(512) void k_scanpartial(const unsigned* __restrict__ partial,
                                                     unsigned* __restrict__ blockoff,
                                                     unsigned* __restrict__ offsets,
                                                     int nb, int N) {
    __shared__ unsigned s[512];
    int t = threadIdx.x;
    unsigned v = (t < nb) ? partial[t] : 0u;
    s[t] = v;
    __syncthreads();
    for (int off = 1; off < 512; off <<= 1) {
        unsigned a = (t >= off) ? s[t - off] : 0u;
        __syncthreads();
        s[t] += a;
        __syncthreads();
    }
    if (t < nb) blockoff[t] = s[t] - v;       // exclusive
    if (t == nb - 1) offsets[N] = s[t];       // total = E
}

__global__ __launch_bounds__(256) void k_offsets(const unsigned* __restrict__ deg,
                                                 const unsigned* __restrict__ blockoff,
                                                 unsigned* __restrict__ offsets,
                                                 unsigned* __restrict__ cursor, int N) {
    __shared__ unsigned s[256];
    int t = threadIdx.x;
    int i = blockIdx.x * 256 + t;
    unsigned v = (i < N) ? deg[i] : 0u;
    s[t] = v;
    __syncthreads();
    for (int off = 1; off < 256; off <<= 1) {
        unsigned a = (t >= off) ? s[t - off] : 0u;
        __syncthreads();
        s[t] += a;
        __syncthreads();
    }
    if (i < N) {
        unsigned o = blockoff[blockIdx.x] + s[t] - v;
        offsets[i] = o;
        cursor[i] = o;
    }
}

// h1 = (x * norm_src[:,None]) @ W1    [N,128]@[128,64]
__global__ __launch_bounds__(256) void k_gemm1(const float* __restrict__ x,
                                               const float* __restrict__ W1,
                                               const float* __restrict__ norm_s,
                                               float* __restrict__ h1, int N) {
    __shared__ float xT[64][65];
    __shared__ __align__(16) float Ws[64][64];
    const int tid = threadIdx.x;
    const int tx = tid & 15;
    const int ty = tid >> 4;
    const int r0 = blockIdx.x * 64;

    float acc[4][4] = {};

#pragma unroll
    for (int kt = 0; kt < 2; ++kt) {
#pragma unroll
        for (int it = 0; it < 16; ++it) {
            int e = it * 256 + tid;
            int r = e >> 6, k = e & 63;
            int row = r0 + r;
            float v = 0.f;
            if (row < N) v = x[(size_t)row * 128 + kt * 64 + k];
            xT[k][r] = v;
        }
#pragma unroll
        for (int it = 0; it < 16; ++it) {
            int e = it * 256 + tid;
            int k = e >> 6, c = e & 63;
            Ws[k][c] = W1[(size_t)(kt * 64 + k) * 64 + c];
        }
        __syncthreads();
#pragma unroll 8
        for (int k = 0; k < 64; ++k) {
            float4 wv = *(const float4*)&Ws[k][tx * 4];
            float x0 = xT[k][ty * 4 + 0];
            float x1 = xT[k][ty * 4 + 1];
            float x2 = xT[k][ty * 4 + 2];
            float x3 = xT[k][ty * 4 + 3];
            acc[0][0] = fmaf(x0, wv.x, acc[0][0]); acc[0][1] = fmaf(x0, wv.y, acc[0][1]);
            acc[0][2] = fmaf(x0, wv.z, acc[0][2]); acc[0][3] = fmaf(x0, wv.w, acc[0][3]);
            acc[1][0] = fmaf(x1, wv.x, acc[1][0]); acc[1][1] = fmaf(x1, wv.y, acc[1][1]);
            acc[1][2] = fmaf(x1, wv.z, acc[1][2]); acc[1][3] = fmaf(x1, wv.w, acc[1][3]);
            acc[2][0] = fmaf(x2, wv.x, acc[2][0]); acc[2][1] = fmaf(x2, wv.y, acc[2][1]);
            acc[2][2] = fmaf(x2, wv.z, acc[2][2]); acc[2][3] = fmaf(x2, wv.w, acc[2][3]);
            acc[3][0] = fmaf(x3, wv.x, acc[3][0]); acc[3][1] = fmaf(x3, wv.y, acc[3][1]);
            acc[3][2] = fmaf(x3, wv.z, acc[3][2]); acc[3][3] = fmaf(x3, wv.w, acc[3][3]);
        }
        __syncthreads();
    }

#pragma unroll
    for (int i = 0; i < 4; ++i) {
        int row = r0 + ty * 4 + i;
        if (row < N) {
            float ns = norm_s[row];
            float4 o = make_float4(acc[i][0] * ns, acc[i][1] * ns,
                                   acc[i][2] * ns, acc[i][3] * ns);
            *(float4*)&h1[(size_t)row * 64 + tx * 4] = o;
        }
    }
}

// One wave per node: register-accumulate h1[src] over in-edges, then fused
// relu/norm/dot(w2l) -> s_node.  lane == channel -> each edge is one coalesced
// 256B read from the LLC-resident h1.
__global__ __launch_bounds__(256) void k_agg_rdot(const unsigned* __restrict__ offsets,
                                                  const unsigned* __restrict__ csr,
                                                  const float* __restrict__ h1,
                                                  const float* __restrict__ norm_s,
                                                  const float* __restrict__ norm_d,
                                                  const float* __restrict__ b1,
                                                  const float* __restrict__ w2l,
                                                  float* __restrict__ s_node, int N) {
    const int lane = threadIdx.x & 63;
    const int v = (blockIdx.x * 256 + threadIdx.x) >> 6;
    if (v >= N) return;
    const unsigned beg = offsets[v], end = offsets[v + 1];
    float acc = 0.f;
    for (unsigned base = beg; base < end; base += WAVE) {
        const int n = (int)min((unsigned)WAVE, end - base);
        int sv = (lane < n) ? (int)csr[base + lane] : 0;
        int i = 0;
        for (; i + 4 <= n; i += 4) {
            int s0 = __shfl(sv, i + 0), s1 = __shfl(sv, i + 1);
            int s2 = __shfl(sv, i + 2), s3 = __shfl(sv, i + 3);
            float v0 = h1[(size_t)s0 * 64 + lane];
            float v1 = h1[(size_t)s1 * 64 + lane];
            float v2 = h1[(size_t)s2 * 64 + lane];
            float v3 = h1[(size_t)s3 * 64 + lane];
            acc += v0 + v1 + v2 + v3;
        }
        for (; i < n; ++i) {
            int s = __shfl(sv, i);
            acc += h1[(size_t)s * 64 + lane];
        }
    }
    float t = fmaf(acc, norm_d[v], b1[lane]);
    t = fmaxf(t, 0.f) * w2l[lane];
#pragma unroll
    for (int off = 32; off; off >>= 1) t += __shfl_xor(t, off);
    if (lane == 0) s_node[v] = t * norm_s[v];
}

// out[v] = nd[v] * sum_{in-edges} s_node[src] + c0
__global__ __launch_bounds__(256) void k_out(const unsigned* __restrict__ offsets,
                                             const unsigned* __restrict__ csr,
                                             const float* __restrict__ s_node,
                                             const float* __restrict__ norm_d,
                                             const float* __restrict__ c0,
                                             float* __restrict__ out, int N) {
    int v = blockIdx.x * 256 + threadIdx.x;
    if (v >= N) return;
    unsigned beg = offsets[v], end = offsets[v + 1];
    float sum = 0.f;
    unsigned j = beg;
    for (; j + 4 <= end; j += 4) {
        float a = s_node[csr[j + 0]], b = s_node[csr[j + 1]];
        float c = s_node[csr[j + 2]], d = s_node[csr[j + 3]];
        sum += a + b + c + d;
    }
    for (; j < end; ++j) sum += s_node[csr[j]];
    out[v] = fmaf(sum, norm_d[v], *c0);
}

extern "C" void kernel_launch(void* const* d_in, const int* in_sizes, int n_in,
                              void* d_out, int out_size, void* d_ws, size_t ws_size,
                              hipStream_t stream) {
    const float* x  = (const float*)d_in[0];
    const int*   ei = (const int*)d_in[1];
    const float* W1 = (const float*)d_in[2];
    const float* b1 = (const float*)d_in[3];
    const float* W2 = (const float*)d_in[4];
    const float* b2 = (const float*)d_in[5];
    const float* Wl = (const float*)d_in[6];
    const float* bl = (const float*)d_in[7];

    const int N = in_sizes[0] / 128;
    const int E = in_sizes[1] / 2;
    const int* src = ei;
    const int* dst = ei + E;
    const int NB = (N + 255) / 256;

    const int step   = (N + NRANGE - 1) / NRANGE;     // dst/src range width
    const int chunkE = (E + NCHUNK - 1) / NCHUNK;     // edges per chunk
    const int gridP  = NCHUNK * NRANGE;               // partitioned grid

    char* w = (char*)d_ws;
    auto alloc = [&](size_t bytes) -> void* {
        void* r = (void*)w;
        w += (bytes + 255) & ~(size_t)255;
        return r;
    };
    unsigned* deg_s   = (unsigned*)alloc((size_t)N * 4);
    unsigned* deg_d   = (unsigned*)alloc((size_t)N * 4);
    float*    norm_s  = (float*)alloc((size_t)N * 4);
    float*    norm_d  = (float*)alloc((size_t)N * 4);
    unsigned* offsets = (unsigned*)alloc((size_t)(N + 1) * 4);
    unsigned* cursor  = (unsigned*)alloc((size_t)N * 4);
    unsigned* partial = (unsigned*)alloc((size_t)NB * 4);
    unsigned* blockoff= (unsigned*)alloc((size_t)NB * 4);
    float*    h1      = (float*)alloc((size_t)N * 64 * 4);
    unsigned* csr     = (unsigned*)alloc((size_t)E * 4);
    float*    s_node  = (float*)alloc((size_t)N * 4);
    float*    w2l     = (float*)alloc(64 * 4);
    float*    c0      = (float*)alloc(4);

    float* out = (float*)d_out;

    hipMemsetAsync(deg_s, 0, (size_t)N * 4, stream);
    hipMemsetAsync(deg_d, 0, (size_t)N * 4, stream);

    k_count<<<gridP, 256, 0, stream>>>(src, dst, deg_s, deg_d, E, step, chunkE);
    k_w2l<<<1, 64, 0, stream>>>(W2, b2, Wl, bl, w2l, c0);
    k_norm<<<NB, 256, 0, stream>>>(deg_s, deg_d, norm_s, norm_d, N);

    k_blocksum<<<NB, 256, 0, stream>>>(deg_d, partial, N);
    k_scanpartial<<<1, 512, 0, stream>>>(partial, blockoff, offsets, NB, N);
    k_offsets<<<NB, 256, 0, stream>>>(deg_d, blockoff, offsets, cursor, N);
    k_fill<<<gridP, 256, 0, stream>>>(src, dst, cursor, csr, E, step, chunkE);

    k_gemm1<<<(N + 63) / 64, 256, 0, stream>>>(x, W1, norm_s, h1, N);

    k_agg_rdot<<<(N + 3) / 4, 256, 0, stream>>>(offsets, csr, h1, norm_s, norm_d,
                                                b1, w2l, s_node, N);
    k_out<<<NB, 256, 0, stream>>>(offsets, csr, s_node, norm_d, c0, out, N);
}

// Round 4
// 221.829 us; speedup vs baseline: 2.8395x; 1.5001x over previous
//
#include <hip/hip_runtime.h>

// GCN on MI355X — atomic-free CSR build (LDS histograms) + CSR aggregation.
//
// Algebra: layer2 collapses through the linear head:
//   out = segsum((relu(c1) . (W2@Wl) * ns)[src], dst)*nd + (b2@Wl + bl)
// so only a per-node SCALAR feeds the second aggregation.
//
// R3 change: global atomics proved to cost ~32B of memory-side traffic each
// (they execute at the device coherence point; XCD partitioning doesn't help).
// CSR build now uses per-block LDS histograms (8 node-ranges x C edge-chunks),
// plain coalesced partial flushes, an in-place exclusive prefix over chunks,
// and LDS-atomic cursors in the fill. Zero global atomics anywhere.

#define WAVE 64
#define NRANGE 8

// ---- histogram: blockIdx.y selects src(0)/dst(1); block (r,c) counts its
// edge chunk's nodes falling in range r into LDS, then flushes coalesced. ----
__global__ __launch_bounds__(256) void k_hist(const int* __restrict__ srcArr,
                                              const int* __restrict__ dstArr,
                                              unsigned* __restrict__ partial_s,
                                              unsigned* __restrict__ partial_d,
                                              int E, int B, int C, int chunkE) {
    extern __shared__ unsigned hist[];
    const int r = blockIdx.x & (NRANGE - 1);
    const int c = blockIdx.x >> 3;
    const int lo = r * B;
    const int* nodes = blockIdx.y ? dstArr : srcArr;
    unsigned* partial = blockIdx.y ? partial_d : partial_s;

    for (int b = threadIdx.x; b < B; b += 256) hist[b] = 0u;
    __syncthreads();

    const int beg = c * chunkE, end = min(beg + chunkE, E);
    const int n4 = (end - beg) >> 2;           // beg is 4-aligned (chunkE %4==0)
    const int4* p = (const int4*)(nodes + beg);
    for (int j = threadIdx.x; j < n4; j += 256) {
        int4 v = p[j];
        int a;
        a = v.x - lo; if ((unsigned)a < (unsigned)B) atomicAdd(&hist[a], 1u);
        a = v.y - lo; if ((unsigned)a < (unsigned)B) atomicAdd(&hist[a], 1u);
        a = v.z - lo; if ((unsigned)a < (unsigned)B) atomicAdd(&hist[a], 1u);
        a = v.w - lo; if ((unsigned)a < (unsigned)B) atomicAdd(&hist[a], 1u);
    }
    for (int j = beg + (n4 << 2) + threadIdx.x; j < end; j += 256) {
        int a = nodes[j] - lo;
        if ((unsigned)a < (unsigned)B) atomicAdd(&hist[a], 1u);
    }
    __syncthreads();
    unsigned* outp = partial + (size_t)(r * C + c) * B;
    for (int b = threadIdx.x; b < B; b += 256) outp[b] = hist[b];
}

// ---- per-node: sum partials -> norms/deg_d; partial_d -> exclusive prefix ----
__global__ __launch_bounds__(256) void k_reduce_norm(const unsigned* __restrict__ partial_s,
                                                     unsigned* __restrict__ partial_d,
                                                     float* __restrict__ norm_s,
                                                     float* __restrict__ norm_d,
                                                     unsigned* __restrict__ deg_d,
                                                     int N, int B, int C) {
    int i = blockIdx.x * 256 + threadIdx.x;
    if (i >= N) return;
    int r = i / B, b = i - r * B;
    size_t base = (size_t)r * C * B + b;
    unsigned ds = 0;
    for (int c = 0; c < C; ++c) ds += partial_s[base + (size_t)c * B];
    unsigned dd = 0;
    for (int c = 0; c < C; ++c) {
        size_t ix = base + (size_t)c * B;
        unsigned v = partial_d[ix];
        partial_d[ix] = dd;                    // exclusive prefix over chunks
        dd += v;
    }
    deg_d[i] = dd;
    norm_s[i] = ds ? rsqrtf((float)ds) : 0.0f;
    norm_d[i] = dd ? rsqrtf((float)dd) : 0.0f;
}

// w2l[c] = sum_j W2[c][j]*Wl[j]; c0 = b2.Wl + bl
__global__ void k_w2l(const float* __restrict__ W2, const float* __restrict__ b2,
                      const float* __restrict__ Wl, const float* __restrict__ bl,
                      float* __restrict__ w2l, float* __restrict__ c0) {
    int c = threadIdx.x; // 64 threads
    float acc = 0.f;
#pragma unroll
    for (int j = 0; j < 32; ++j) acc += W2[c * 32 + j] * Wl[j];
    w2l[c] = acc;
    if (c == 0) {
        float s = 0.f;
#pragma unroll
        for (int j = 0; j < 32; ++j) s += b2[j] * Wl[j];
        *c0 = s + bl[0];
    }
}

// ---- scan: deg_d -> exclusive offsets (N+1) ----
__global__ __launch_bounds__(256) void k_blocksum(const unsigned* __restrict__ deg,
                                                  unsigned* __restrict__ partial, int N) {
    __shared__ unsigned sw[4];
    int i = blockIdx.x * 256 + threadIdx.x;
    unsigned v = (i < N) ? deg[i] : 0u;
#pragma unroll
    for (int off = 32; off; off >>= 1) v += __shfl_xor((int)v, off);
    if ((threadIdx.x & 63) == 0) sw[threadIdx.x >> 6] = v;
    __syncthreads();
    if (threadIdx.x == 0) partial[blockIdx.x] = sw[0] + sw[1] + sw[2] + sw[3];
}

__global__ __launch_bounds__(512) void k_scanpartial(const unsigned* __restrict__ partial,
                                                     unsigned* __restrict__ blockoff,
                                                     unsigned* __restrict__ offsets,
                                                     int nb, int N) {
    __shared__ unsigned s[512];
    int t = threadIdx.x;
    unsigned v = (t < nb) ? partial[t] : 0u;
    s[t] = v;
    __syncthreads();
    for (int off = 1; off < 512; off <<= 1) {
        unsigned a = (t >= off) ? s[t - off] : 0u;
        __syncthreads();
        s[t] += a;
        __syncthreads();
    }
    if (t < nb) blockoff[t] = s[t] - v;       // exclusive
    if (t == nb - 1) offsets[N] = s[t];       // total = E
}

__global__ __launch_bounds__(256) void k_offsets(const unsigned* __restrict__ deg,
                                                 const unsigned* __restrict__ blockoff,
                                                 unsigned* __restrict__ offsets, int N) {
    __shared__ unsigned s[256];
    int t = threadIdx.x;
    int i = blockIdx.x * 256 + t;
    unsigned v = (i < N) ? deg[i] : 0u;
    s[t] = v;
    __syncthreads();
    for (int off = 1; off < 256; off <<= 1) {
        unsigned a = (t >= off) ? s[t - off] : 0u;
        __syncthreads();
        s[t] += a;
        __syncthreads();
    }
    if (i < N) offsets[i] = blockoff[blockIdx.x] + s[t] - v;
}

// ---- fill: LDS cursors seeded from offsets + chunk-prefix; LDS atomics only ----
__global__ __launch_bounds__(256) void k_fill(const int* __restrict__ src,
                                              const int* __restrict__ dst,
                                              const unsigned* __restrict__ offsets,
                                              const unsigned* __restrict__ rel,
                                              unsigned* __restrict__ csr,
                                              int N, int E, int B, int C, int chunkE) {
    extern __shared__ unsigned curs[];
    const int r = blockIdx.x & (NRANGE - 1);
    const int c = blockIdx.x >> 3;
    const int lo = r * B;
    const int bins = min(B, N - lo);
    const unsigned* relp = rel + (size_t)(r * C + c) * B;
    for (int b = threadIdx.x; b < bins; b += 256)
        curs[b] = offsets[lo + b] + relp[b];
    __syncthreads();

    const int beg = c * chunkE, end = min(beg + chunkE, E);
    const int n4 = (end - beg) >> 2;
    const int4* pd = (const int4*)(dst + beg);
    const int4* ps = (const int4*)(src + beg);
    for (int j = threadIdx.x; j < n4; j += 256) {
        int4 d4 = pd[j];
        int4 s4 = ps[j];
        int a;
        a = d4.x - lo; if ((unsigned)a < (unsigned)bins) csr[atomicAdd(&curs[a], 1u)] = (unsigned)s4.x;
        a = d4.y - lo; if ((unsigned)a < (unsigned)bins) csr[atomicAdd(&curs[a], 1u)] = (unsigned)s4.y;
        a = d4.z - lo; if ((unsigned)a < (unsigned)bins) csr[atomicAdd(&curs[a], 1u)] = (unsigned)s4.z;
        a = d4.w - lo; if ((unsigned)a < (unsigned)bins) csr[atomicAdd(&curs[a], 1u)] = (unsigned)s4.w;
    }
    for (int j = beg + (n4 << 2) + threadIdx.x; j < end; j += 256) {
        int a = dst[j] - lo;
        if ((unsigned)a < (unsigned)bins) csr[atomicAdd(&curs[a], 1u)] = (unsigned)src[j];
    }
}

// h1 = (x * norm_src[:,None]) @ W1    [N,128]@[128,64]
__global__ __launch_bounds__(256) void k_gemm1(const float* __restrict__ x,
                                               const float* __restrict__ W1,
                                               const float* __restrict__ norm_s,
                                               float* __restrict__ h1, int N) {
    __shared__ float xT[64][65];
    __shared__ __align__(16) float Ws[64][64];
    const int tid = threadIdx.x;
    const int tx = tid & 15;
    const int ty = tid >> 4;
    const int r0 = blockIdx.x * 64;

    float acc[4][4] = {};

#pragma unroll
    for (int kt = 0; kt < 2; ++kt) {
#pragma unroll
        for (int it = 0; it < 16; ++it) {
            int e = it * 256 + tid;
            int r = e >> 6, k = e & 63;
            int row = r0 + r;
            float v = 0.f;
            if (row < N) v = x[(size_t)row * 128 + kt * 64 + k];
            xT[k][r] = v;
        }
#pragma unroll
        for (int it = 0; it < 16; ++it) {
            int e = it * 256 + tid;
            int k = e >> 6, cc = e & 63;
            Ws[k][cc] = W1[(size_t)(kt * 64 + k) * 64 + cc];
        }
        __syncthreads();
#pragma unroll 8
        for (int k = 0; k < 64; ++k) {
            float4 wv = *(const float4*)&Ws[k][tx * 4];
            float x0 = xT[k][ty * 4 + 0];
            float x1 = xT[k][ty * 4 + 1];
            float x2 = xT[k][ty * 4 + 2];
            float x3 = xT[k][ty * 4 + 3];
            acc[0][0] = fmaf(x0, wv.x, acc[0][0]); acc[0][1] = fmaf(x0, wv.y, acc[0][1]);
            acc[0][2] = fmaf(x0, wv.z, acc[0][2]); acc[0][3] = fmaf(x0, wv.w, acc[0][3]);
            acc[1][0] = fmaf(x1, wv.x, acc[1][0]); acc[1][1] = fmaf(x1, wv.y, acc[1][1]);
            acc[1][2] = fmaf(x1, wv.z, acc[1][2]); acc[1][3] = fmaf(x1, wv.w, acc[1][3]);
            acc[2][0] = fmaf(x2, wv.x, acc[2][0]); acc[2][1] = fmaf(x2, wv.y, acc[2][1]);
            acc[2][2] = fmaf(x2, wv.z, acc[2][2]); acc[2][3] = fmaf(x2, wv.w, acc[2][3]);
            acc[3][0] = fmaf(x3, wv.x, acc[3][0]); acc[3][1] = fmaf(x3, wv.y, acc[3][1]);
            acc[3][2] = fmaf(x3, wv.z, acc[3][2]); acc[3][3] = fmaf(x3, wv.w, acc[3][3]);
        }
        __syncthreads();
    }

#pragma unroll
    for (int i = 0; i < 4; ++i) {
        int row = r0 + ty * 4 + i;
        if (row < N) {
            float ns = norm_s[row];
            float4 o = make_float4(acc[i][0] * ns, acc[i][1] * ns,
                                   acc[i][2] * ns, acc[i][3] * ns);
            *(float4*)&h1[(size_t)row * 64 + tx * 4] = o;
        }
    }
}

// One wave per node: register-accumulate h1[src] over in-edges, then fused
// relu/norm/dot(w2l) -> s_node.
__global__ __launch_bounds__(256) void k_agg_rdot(const unsigned* __restrict__ offsets,
                                                  const unsigned* __restrict__ csr,
                                                  const float* __restrict__ h1,
                                                  const float* __restrict__ norm_s,
                                                  const float* __restrict__ norm_d,
                                                  const float* __restrict__ b1,
                                                  const float* __restrict__ w2l,
                                                  float* __restrict__ s_node, int N) {
    const int lane = threadIdx.x & 63;
    const int v = (blockIdx.x * 256 + threadIdx.x) >> 6;
    if (v >= N) return;
    const unsigned beg = offsets[v], end = offsets[v + 1];
    float acc = 0.f;
    for (unsigned base = beg; base < end; base += WAVE) {
        const int n = (int)min((unsigned)WAVE, end - base);
        int sv = (lane < n) ? (int)csr[base + lane] : 0;
        int i = 0;
        for (; i + 4 <= n; i += 4) {
            int s0 = __shfl(sv, i + 0), s1 = __shfl(sv, i + 1);
            int s2 = __shfl(sv, i + 2), s3 = __shfl(sv, i + 3);
            float v0 = h1[(size_t)s0 * 64 + lane];
            float v1 = h1[(size_t)s1 * 64 + lane];
            float v2 = h1[(size_t)s2 * 64 + lane];
            float v3 = h1[(size_t)s3 * 64 + lane];
            acc += v0 + v1 + v2 + v3;
        }
        for (; i < n; ++i) {
            int s = __shfl(sv, i);
            acc += h1[(size_t)s * 64 + lane];
        }
    }
    float t = fmaf(acc, norm_d[v], b1[lane]);
    t = fmaxf(t, 0.f) * w2l[lane];
#pragma unroll
    for (int off = 32; off; off >>= 1) t += __shfl_xor(t, off);
    if (lane == 0) s_node[v] = t * norm_s[v];
}

// out[v] = nd[v] * sum_{in-edges} s_node[src] + c0
__global__ __launch_bounds__(256) void k_out(const unsigned* __restrict__ offsets,
                                             const unsigned* __restrict__ csr,
                                             const float* __restrict__ s_node,
                                             const float* __restrict__ norm_d,
                                             const float* __restrict__ c0,
                                             float* __restrict__ out, int N) {
    int v = blockIdx.x * 256 + threadIdx.x;
    if (v >= N) return;
    unsigned beg = offsets[v], end = offsets[v + 1];
    float sum = 0.f;
    unsigned j = beg;
    for (; j + 4 <= end; j += 4) {
        float a = s_node[csr[j + 0]], b = s_node[csr[j + 1]];
        float c = s_node[csr[j + 2]], d = s_node[csr[j + 3]];
        sum += a + b + c + d;
    }
    for (; j < end; ++j) sum += s_node[csr[j]];
    out[v] = fmaf(sum, norm_d[v], *c0);
}

extern "C" void kernel_launch(void* const* d_in, const int* in_sizes, int n_in,
                              void* d_out, int out_size, void* d_ws, size_t ws_size,
                              hipStream_t stream) {
    const float* x  = (const float*)d_in[0];
    const int*   ei = (const int*)d_in[1];
    const float* W1 = (const float*)d_in[2];
    const float* b1 = (const float*)d_in[3];
    const float* W2 = (const float*)d_in[4];
    const float* b2 = (const float*)d_in[5];
    const float* Wl = (const float*)d_in[6];
    const float* bl = (const float*)d_in[7];

    const int N = in_sizes[0] / 128;
    const int E = in_sizes[1] / 2;
    const int* src = ei;
    const int* dst = ei + E;
    const int NB = (N + 255) / 256;
    const int B = (N + NRANGE - 1) / NRANGE;       // bins per range (<=16K -> 64KB LDS cap ok)

    // pick chunk count C so partials fit the workspace
    size_t baseBytes = 0;
    {
        auto pad = [](size_t b) { return (b + 255) & ~(size_t)255; };
        baseBytes = pad((size_t)N * 4) * 3 + pad((size_t)(N + 1) * 4) +
                    pad((size_t)NB * 4) * 2 + pad((size_t)N * 64 * 4) +
                    pad((size_t)E * 4) + pad((size_t)N * 4) + pad(64 * 4) + pad(4);
    }
    int C = 32;
    while (C > 4 && baseBytes + 2ull * NRANGE * C * B * 4ull > ws_size) C >>= 1;
    const int chunkE = (((E + C - 1) / C) + 3) & ~3;

    char* w = (char*)d_ws;
    auto alloc = [&](size_t bytes) -> void* {
        void* r = (void*)w;
        w += (bytes + 255) & ~(size_t)255;
        return r;
    };
    float*    norm_s    = (float*)alloc((size_t)N * 4);
    float*    norm_d    = (float*)alloc((size_t)N * 4);
    unsigned* deg_d     = (unsigned*)alloc((size_t)N * 4);
    unsigned* offsets   = (unsigned*)alloc((size_t)(N + 1) * 4);
    unsigned* partial   = (unsigned*)alloc((size_t)NB * 4);
    unsigned* blockoff  = (unsigned*)alloc((size_t)NB * 4);
    float*    h1        = (float*)alloc((size_t)N * 64 * 4);
    unsigned* csr       = (unsigned*)alloc((size_t)E * 4);
    float*    s_node    = (float*)alloc((size_t)N * 4);
    float*    w2l       = (float*)alloc(64 * 4);
    float*    c0        = (float*)alloc(4);
    unsigned* partial_s = (unsigned*)alloc((size_t)NRANGE * C * B * 4);
    unsigned* partial_d = (unsigned*)alloc((size_t)NRANGE * C * B * 4);

    float* out = (float*)d_out;
    const size_t ldsB = (size_t)B * 4;

    k_hist<<<dim3(NRANGE * C, 2), 256, ldsB, stream>>>(src, dst, partial_s, partial_d,
                                                       E, B, C, chunkE);
    k_w2l<<<1, 64, 0, stream>>>(W2, b2, Wl, bl, w2l, c0);
    k_reduce_norm<<<NB, 256, 0, stream>>>(partial_s, partial_d, norm_s, norm_d,
                                          deg_d, N, B, C);

    k_blocksum<<<NB, 256, 0, stream>>>(deg_d, partial, N);
    k_scanpartial<<<1, 512, 0, stream>>>(partial, blockoff, offsets, NB, N);
    k_offsets<<<NB, 256, 0, stream>>>(deg_d, blockoff, offsets, N);

    k_fill<<<NRANGE * C, 256, ldsB, stream>>>(src, dst, offsets, partial_d, csr,
                                              N, E, B, C, chunkE);

    k_gemm1<<<(N + 63) / 64, 256, 0, stream>>>(x, W1, norm_s, h1, N);

    k_agg_rdot<<<(N + 3) / 4, 256, 0, stream>>>(offsets, csr, h1, norm_s, norm_d,
                                                b1, w2l, s_node, N);
    k_out<<<NB, 256, 0, stream>>>(offsets, csr, s_node, norm_d, c0, out, N);
}

// Round 5
// 207.833 us; speedup vs baseline: 3.0307x; 1.0673x over previous
//
#include <hip/hip_runtime.h>
#include <hip/hip_fp16.h>

// GCN on MI355X — atomic-free CSR build + fp16 gather aggregation.
//
// Algebra: layer2 collapses through the linear head:
//   out = segsum((relu(c1) . (W2@Wl) * ns)[src], dst)*nd + (b2@Wl + bl)
// so only a per-node SCALAR feeds the second aggregation.
//
// R4 change: k_agg_rdot was HBM/L2-fill bound (FETCH 180MB, 410MB of 256B-row
// gathers from a 25.6MB fp32 h1). h1 is now fp16 (12.8MB): per edge 128B, wave
// processes 2 edges/step (half-wave each, __half2 per lane = 256B/instr),
// 8 edges in flight. fp16 error ~5e-4 << 3.2e-3 threshold.

#define WAVE 64
#define NRANGE 8

// ---- histogram: blockIdx.y selects src(0)/dst(1); block (r,c) counts its
// edge chunk's nodes falling in range r into LDS, then flushes coalesced. ----
__global__ __launch_bounds__(256) void k_hist(const int* __restrict__ srcArr,
                                              const int* __restrict__ dstArr,
                                              unsigned* __restrict__ partial_s,
                                              unsigned* __restrict__ partial_d,
                                              int E, int B, int C, int chunkE) {
    extern __shared__ unsigned hist[];
    const int r = blockIdx.x & (NRANGE - 1);
    const int c = blockIdx.x >> 3;
    const int lo = r * B;
    const int* nodes = blockIdx.y ? dstArr : srcArr;
    unsigned* partial = blockIdx.y ? partial_d : partial_s;

    for (int b = threadIdx.x; b < B; b += 256) hist[b] = 0u;
    __syncthreads();

    const int beg = c * chunkE, end = min(beg + chunkE, E);
    const int n4 = (end - beg) >> 2;           // beg is 4-aligned (chunkE %4==0)
    const int4* p = (const int4*)(nodes + beg);
    for (int j = threadIdx.x; j < n4; j += 256) {
        int4 v = p[j];
        int a;
        a = v.x - lo; if ((unsigned)a < (unsigned)B) atomicAdd(&hist[a], 1u);
        a = v.y - lo; if ((unsigned)a < (unsigned)B) atomicAdd(&hist[a], 1u);
        a = v.z - lo; if ((unsigned)a < (unsigned)B) atomicAdd(&hist[a], 1u);
        a = v.w - lo; if ((unsigned)a < (unsigned)B) atomicAdd(&hist[a], 1u);
    }
    for (int j = beg + (n4 << 2) + threadIdx.x; j < end; j += 256) {
        int a = nodes[j] - lo;
        if ((unsigned)a < (unsigned)B) atomicAdd(&hist[a], 1u);
    }
    __syncthreads();
    unsigned* outp = partial + (size_t)(r * C + c) * B;
    for (int b = threadIdx.x; b < B; b += 256) outp[b] = hist[b];
}

// ---- per-node: sum partials -> norms/deg_d; partial_d -> exclusive prefix ----
__global__ __launch_bounds__(256) void k_reduce_norm(const unsigned* __restrict__ partial_s,
                                                     unsigned* __restrict__ partial_d,
                                                     float* __restrict__ norm_s,
                                                     float* __restrict__ norm_d,
                                                     unsigned* __restrict__ deg_d,
                                                     int N, int B, int C) {
    int i = blockIdx.x * 256 + threadIdx.x;
    if (i >= N) return;
    int r = i / B, b = i - r * B;
    size_t base = (size_t)r * C * B + b;
    unsigned ds = 0;
    for (int c = 0; c < C; ++c) ds += partial_s[base + (size_t)c * B];
    unsigned dd = 0;
    for (int c = 0; c < C; ++c) {
        size_t ix = base + (size_t)c * B;
        unsigned v = partial_d[ix];
        partial_d[ix] = dd;                    // exclusive prefix over chunks
        dd += v;
    }
    deg_d[i] = dd;
    norm_s[i] = ds ? rsqrtf((float)ds) : 0.0f;
    norm_d[i] = dd ? rsqrtf((float)dd) : 0.0f;
}

// w2l[c] = sum_j W2[c][j]*Wl[j]; c0 = b2.Wl + bl
__global__ void k_w2l(const float* __restrict__ W2, const float* __restrict__ b2,
                      const float* __restrict__ Wl, const float* __restrict__ bl,
                      float* __restrict__ w2l, float* __restrict__ c0) {
    int c = threadIdx.x; // 64 threads
    float acc = 0.f;
#pragma unroll
    for (int j = 0; j < 32; ++j) acc += W2[c * 32 + j] * Wl[j];
    w2l[c] = acc;
    if (c == 0) {
        float s = 0.f;
#pragma unroll
        for (int j = 0; j < 32; ++j) s += b2[j] * Wl[j];
        *c0 = s + bl[0];
    }
}

// ---- scan: deg_d -> exclusive offsets (N+1) ----
__global__ __launch_bounds__(256) void k_blocksum(const unsigned* __restrict__ deg,
                                                  unsigned* __restrict__ partial, int N) {
    __shared__ unsigned sw[4];
    int i = blockIdx.x * 256 + threadIdx.x;
    unsigned v = (i < N) ? deg[i] : 0u;
#pragma unroll
    for (int off = 32; off; off >>= 1) v += __shfl_xor((int)v, off);
    if ((threadIdx.x & 63) == 0) sw[threadIdx.x >> 6] = v;
    __syncthreads();
    if (threadIdx.x == 0) partial[blockIdx.x] = sw[0] + sw[1] + sw[2] + sw[3];
}

__global__ __launch_bounds__(512) void k_scanpartial(const unsigned* __restrict__ partial,
                                                     unsigned* __restrict__ blockoff,
                                                     unsigned* __restrict__ offsets,
                                                     int nb, int N) {
    __shared__ unsigned s[512];
    int t = threadIdx.x;
    unsigned v = (t < nb) ? partial[t] : 0u;
    s[t] = v;
    __syncthreads();
    for (int off = 1; off < 512; off <<= 1) {
        unsigned a = (t >= off) ? s[t - off] : 0u;
        __syncthreads();
        s[t] += a;
        __syncthreads();
    }
    if (t < nb) blockoff[t] = s[t] - v;       // exclusive
    if (t == nb - 1) offsets[N] = s[t];       // total = E
}

__global__ __launch_bounds__(256) void k_offsets(const unsigned* __restrict__ deg,
                                                 const unsigned* __restrict__ blockoff,
                                                 unsigned* __restrict__ offsets, int N) {
    __shared__ unsigned s[256];
    int t = threadIdx.x;
    int i = blockIdx.x * 256 + t;
    unsigned v = (i < N) ? deg[i] : 0u;
    s[t] = v;
    __syncthreads();
    for (int off = 1; off < 256; off <<= 1) {
        unsigned a = (t >= off) ? s[t - off] : 0u;
        __syncthreads();
        s[t] += a;
        __syncthreads();
    }
    if (i < N) offsets[i] = blockoff[blockIdx.x] + s[t] - v;
}

// ---- fill: LDS cursors seeded from offsets + chunk-prefix; LDS atomics only ----
__global__ __launch_bounds__(256) void k_fill(const int* __restrict__ src,
                                              const int* __restrict__ dst,
                                              const unsigned* __restrict__ offsets,
                                              const unsigned* __restrict__ rel,
                                              unsigned* __restrict__ csr,
                                              int N, int E, int B, int C, int chunkE) {
    extern __shared__ unsigned curs[];
    const int r = blockIdx.x & (NRANGE - 1);
    const int c = blockIdx.x >> 3;
    const int lo = r * B;
    const int bins = min(B, N - lo);
    const unsigned* relp = rel + (size_t)(r * C + c) * B;
    for (int b = threadIdx.x; b < bins; b += 256)
        curs[b] = offsets[lo + b] + relp[b];
    __syncthreads();

    const int beg = c * chunkE, end = min(beg + chunkE, E);
    const int n4 = (end - beg) >> 2;
    const int4* pd = (const int4*)(dst + beg);
    const int4* ps = (const int4*)(src + beg);
    for (int j = threadIdx.x; j < n4; j += 256) {
        int4 d4 = pd[j];
        int4 s4 = ps[j];
        int a;
        a = d4.x - lo; if ((unsigned)a < (unsigned)bins) csr[atomicAdd(&curs[a], 1u)] = (unsigned)s4.x;
        a = d4.y - lo; if ((unsigned)a < (unsigned)bins) csr[atomicAdd(&curs[a], 1u)] = (unsigned)s4.y;
        a = d4.z - lo; if ((unsigned)a < (unsigned)bins) csr[atomicAdd(&curs[a], 1u)] = (unsigned)s4.z;
        a = d4.w - lo; if ((unsigned)a < (unsigned)bins) csr[atomicAdd(&curs[a], 1u)] = (unsigned)s4.w;
    }
    for (int j = beg + (n4 << 2) + threadIdx.x; j < end; j += 256) {
        int a = dst[j] - lo;
        if ((unsigned)a < (unsigned)bins) csr[atomicAdd(&curs[a], 1u)] = (unsigned)src[j];
    }
}

// h1h = fp16( (x * norm_src[:,None]) @ W1 )    [N,128]@[128,64]
__global__ __launch_bounds__(256) void k_gemm1(const float* __restrict__ x,
                                               const float* __restrict__ W1,
                                               const float* __restrict__ norm_s,
                                               __half* __restrict__ h1h, int N) {
    __shared__ float xT[64][65];
    __shared__ __align__(16) float Ws[64][64];
    const int tid = threadIdx.x;
    const int tx = tid & 15;
    const int ty = tid >> 4;
    const int r0 = blockIdx.x * 64;

    float acc[4][4] = {};

#pragma unroll
    for (int kt = 0; kt < 2; ++kt) {
#pragma unroll
        for (int it = 0; it < 16; ++it) {
            int e = it * 256 + tid;
            int r = e >> 6, k = e & 63;
            int row = r0 + r;
            float v = 0.f;
            if (row < N) v = x[(size_t)row * 128 + kt * 64 + k];
            xT[k][r] = v;
        }
#pragma unroll
        for (int it = 0; it < 16; ++it) {
            int e = it * 256 + tid;
            int k = e >> 6, cc = e & 63;
            Ws[k][cc] = W1[(size_t)(kt * 64 + k) * 64 + cc];
        }
        __syncthreads();
#pragma unroll 8
        for (int k = 0; k < 64; ++k) {
            float4 wv = *(const float4*)&Ws[k][tx * 4];
            float x0 = xT[k][ty * 4 + 0];
            float x1 = xT[k][ty * 4 + 1];
            float x2 = xT[k][ty * 4 + 2];
            float x3 = xT[k][ty * 4 + 3];
            acc[0][0] = fmaf(x0, wv.x, acc[0][0]); acc[0][1] = fmaf(x0, wv.y, acc[0][1]);
            acc[0][2] = fmaf(x0, wv.z, acc[0][2]); acc[0][3] = fmaf(x0, wv.w, acc[0][3]);
            acc[1][0] = fmaf(x1, wv.x, acc[1][0]); acc[1][1] = fmaf(x1, wv.y, acc[1][1]);
            acc[1][2] = fmaf(x1, wv.z, acc[1][2]); acc[1][3] = fmaf(x1, wv.w, acc[1][3]);
            acc[2][0] = fmaf(x2, wv.x, acc[2][0]); acc[2][1] = fmaf(x2, wv.y, acc[2][1]);
            acc[2][2] = fmaf(x2, wv.z, acc[2][2]); acc[2][3] = fmaf(x2, wv.w, acc[2][3]);
            acc[3][0] = fmaf(x3, wv.x, acc[3][0]); acc[3][1] = fmaf(x3, wv.y, acc[3][1]);
            acc[3][2] = fmaf(x3, wv.z, acc[3][2]); acc[3][3] = fmaf(x3, wv.w, acc[3][3]);
        }
        __syncthreads();
    }

#pragma unroll
    for (int i = 0; i < 4; ++i) {
        int row = r0 + ty * 4 + i;
        if (row < N) {
            float ns = norm_s[row];
            __half2 lo = __floats2half2_rn(acc[i][0] * ns, acc[i][1] * ns);
            __half2 hi = __floats2half2_rn(acc[i][2] * ns, acc[i][3] * ns);
            uint2 pk;
            pk.x = *(unsigned*)&lo;
            pk.y = *(unsigned*)&hi;
            *(uint2*)&h1h[(size_t)row * 64 + tx * 4] = pk;
        }
    }
}

// One wave per node. Two edges per step: lanes 0-31 = even slot, 32-63 = odd.
// Each lane loads __half2 (2 channels) -> 256B/instruction, 8 edges in flight.
__global__ __launch_bounds__(256) void k_agg_rdot(const unsigned* __restrict__ offsets,
                                                  const unsigned* __restrict__ csr,
                                                  const __half* __restrict__ h1h,
                                                  const float* __restrict__ norm_s,
                                                  const float* __restrict__ norm_d,
                                                  const float* __restrict__ b1,
                                                  const float* __restrict__ w2l,
                                                  float* __restrict__ s_node, int N) {
    const int lane = threadIdx.x & 63;
    const int slot = lane >> 5;    // which edge of the pair
    const int p = lane & 31;       // channel pair -> channels 2p, 2p+1
    const int v = (blockIdx.x * 256 + threadIdx.x) >> 6;
    if (v >= N) return;
    const unsigned beg = offsets[v], end = offsets[v + 1];

    float ax = 0.f, ay = 0.f;
    for (unsigned base = beg; base < end; base += WAVE) {
        const int n = (int)min((unsigned)WAVE, end - base);
        int sv = (lane < n) ? (int)csr[base + lane] : 0;
        int i = 0;
        for (; i + 8 <= n; i += 8) {   // 4 independent 256B gathers in flight
            int s0 = __shfl(sv, i + 0 + slot);
            int s1 = __shfl(sv, i + 2 + slot);
            int s2 = __shfl(sv, i + 4 + slot);
            int s3 = __shfl(sv, i + 6 + slot);
            unsigned u0 = *(const unsigned*)&h1h[(size_t)s0 * 64 + 2 * p];
            unsigned u1 = *(const unsigned*)&h1h[(size_t)s1 * 64 + 2 * p];
            unsigned u2 = *(const unsigned*)&h1h[(size_t)s2 * 64 + 2 * p];
            unsigned u3 = *(const unsigned*)&h1h[(size_t)s3 * 64 + 2 * p];
            float2 f0 = __half22float2(*(__half2*)&u0);
            float2 f1 = __half22float2(*(__half2*)&u1);
            float2 f2 = __half22float2(*(__half2*)&u2);
            float2 f3 = __half22float2(*(__half2*)&u3);
            ax += (f0.x + f1.x) + (f2.x + f3.x);
            ay += (f0.y + f1.y) + (f2.y + f3.y);
        }
        for (; i < n; i += 2) {
            int e = i + slot;
            int s = __shfl(sv, min(e, n - 1));
            if (e < n) {
                unsigned u = *(const unsigned*)&h1h[(size_t)s * 64 + 2 * p];
                float2 f = __half22float2(*(__half2*)&u);
                ax += f.x; ay += f.y;
            }
        }
    }
    // merge the two edge-slots: lanes l and l^32 hold the same channel pair
    ax += __shfl_xor(ax, 32);
    ay += __shfl_xor(ay, 32);

    float nd = norm_d[v];
    float t = fmaxf(fmaf(ax, nd, b1[2 * p]), 0.f) * w2l[2 * p]
            + fmaxf(fmaf(ay, nd, b1[2 * p + 1]), 0.f) * w2l[2 * p + 1];
#pragma unroll
    for (int off = 16; off; off >>= 1) t += __shfl_xor(t, off);
    if (lane == 0) s_node[v] = t * norm_s[v];
}

// out[v] = nd[v] * sum_{in-edges} s_node[src] + c0
__global__ __launch_bounds__(256) void k_out(const unsigned* __restrict__ offsets,
                                             const unsigned* __restrict__ csr,
                                             const float* __restrict__ s_node,
                                             const float* __restrict__ norm_d,
                                             const float* __restrict__ c0,
                                             float* __restrict__ out, int N) {
    int v = blockIdx.x * 256 + threadIdx.x;
    if (v >= N) return;
    unsigned beg = offsets[v], end = offsets[v + 1];
    float sum = 0.f;
    unsigned j = beg;
    for (; j + 4 <= end; j += 4) {
        float a = s_node[csr[j + 0]], b = s_node[csr[j + 1]];
        float c = s_node[csr[j + 2]], d = s_node[csr[j + 3]];
        sum += a + b + c + d;
    }
    for (; j < end; ++j) sum += s_node[csr[j]];
    out[v] = fmaf(sum, norm_d[v], *c0);
}

extern "C" void kernel_launch(void* const* d_in, const int* in_sizes, int n_in,
                              void* d_out, int out_size, void* d_ws, size_t ws_size,
                              hipStream_t stream) {
    const float* x  = (const float*)d_in[0];
    const int*   ei = (const int*)d_in[1];
    const float* W1 = (const float*)d_in[2];
    const float* b1 = (const float*)d_in[3];
    const float* W2 = (const float*)d_in[4];
    const float* b2 = (const float*)d_in[5];
    const float* Wl = (const float*)d_in[6];
    const float* bl = (const float*)d_in[7];

    const int N = in_sizes[0] / 128;
    const int E = in_sizes[1] / 2;
    const int* src = ei;
    const int* dst = ei + E;
    const int NB = (N + 255) / 256;
    const int B = (N + NRANGE - 1) / NRANGE;       // bins per range

    // pick chunk count C so partials fit the workspace
    size_t baseBytes = 0;
    {
        auto pad = [](size_t b) { return (b + 255) & ~(size_t)255; };
        baseBytes = pad((size_t)N * 4) * 3 + pad((size_t)(N + 1) * 4) +
                    pad((size_t)NB * 4) * 2 + pad((size_t)N * 64 * 2) +
                    pad((size_t)E * 4) + pad((size_t)N * 4) + pad(64 * 4) + pad(4);
    }
    int C = 32;
    while (C > 4 && baseBytes + 2ull * NRANGE * C * B * 4ull > ws_size) C >>= 1;
    const int chunkE = (((E + C - 1) / C) + 3) & ~3;

    char* w = (char*)d_ws;
    auto alloc = [&](size_t bytes) -> void* {
        void* r = (void*)w;
        w += (bytes + 255) & ~(size_t)255;
        return r;
    };
    float*    norm_s    = (float*)alloc((size_t)N * 4);
    float*    norm_d    = (float*)alloc((size_t)N * 4);
    unsigned* deg_d     = (unsigned*)alloc((size_t)N * 4);
    unsigned* offsets   = (unsigned*)alloc((size_t)(N + 1) * 4);
    unsigned* partial   = (unsigned*)alloc((size_t)NB * 4);
    unsigned* blockoff  = (unsigned*)alloc((size_t)NB * 4);
    __half*   h1h       = (__half*)alloc((size_t)N * 64 * 2);
    unsigned* csr       = (unsigned*)alloc((size_t)E * 4);
    float*    s_node    = (float*)alloc((size_t)N * 4);
    float*    w2l       = (float*)alloc(64 * 4);
    float*    c0        = (float*)alloc(4);
    unsigned* partial_s = (unsigned*)alloc((size_t)NRANGE * C * B * 4);
    unsigned* partial_d = (unsigned*)alloc((size_t)NRANGE * C * B * 4);

    float* out = (float*)d_out;
    const size_t ldsB = (size_t)B * 4;

    k_hist<<<dim3(NRANGE * C, 2), 256, ldsB, stream>>>(src, dst, partial_s, partial_d,
                                                       E, B, C, chunkE);
    k_w2l<<<1, 64, 0, stream>>>(W2, b2, Wl, bl, w2l, c0);
    k_reduce_norm<<<NB, 256, 0, stream>>>(partial_s, partial_d, norm_s, norm_d,
                                          deg_d, N, B, C);

    k_blocksum<<<NB, 256, 0, stream>>>(deg_d, partial, N);
    k_scanpartial<<<1, 512, 0, stream>>>(partial, blockoff, offsets, NB, N);
    k_offsets<<<NB, 256, 0, stream>>>(deg_d, blockoff, offsets, N);

    k_fill<<<NRANGE * C, 256, ldsB, stream>>>(src, dst, offsets, partial_d, csr,
                                              N, E, B, C, chunkE);

    k_gemm1<<<(N + 63) / 64, 256, 0, stream>>>(x, W1, norm_s, h1h, N);

    k_agg_rdot<<<(N + 3) / 4, 256, 0, stream>>>(offsets, csr, h1h, norm_s, norm_d,
                                                b1, w2l, s_node, N);
    k_out<<<NB, 256, 0, stream>>>(offsets, csr, s_node, norm_d, c0, out, N);
}

// Round 6
// 196.309 us; speedup vs baseline: 3.2087x; 1.0587x over previous
//
#include <hip/hip_runtime.h>
#include <hip/hip_fp16.h>

// GCN on MI355X — atomic-free CSR build + fp16 gather aggregation + MFMA GEMM.
//
// Algebra: layer2 collapses through the linear head:
//   out = segsum((relu(c1) . (W2@Wl) * ns)[src], dst)*nd + (b2@Wl + bl)
// so only a per-node SCALAR feeds the second aggregation.
//
// R5 change: k_gemm1 (60us, VALU fp32) -> MFMA 16x16x32_f16 (output is fp16
// anyway). W1 pre-transposed to fp16 once (k_wt); B-fragments live in VGPRs
// (identical for all waves); x tile staged to LDS fp16 with XOR swizzle
// (byte ^= (r&7)<<4) for conflict-free ds_read_b128 A-fragments.

#define WAVE 64
#define NRANGE 8

typedef _Float16 f16x8 __attribute__((ext_vector_type(8)));
typedef float f32x4 __attribute__((ext_vector_type(4)));

// ---- histogram: blockIdx.y selects src(0)/dst(1); block (r,c) counts its
// edge chunk's nodes falling in range r into LDS, then flushes coalesced. ----
__global__ __launch_bounds__(256) void k_hist(const int* __restrict__ srcArr,
                                              const int* __restrict__ dstArr,
                                              unsigned* __restrict__ partial_s,
                                              unsigned* __restrict__ partial_d,
                                              int E, int B, int C, int chunkE) {
    extern __shared__ unsigned hist[];
    const int r = blockIdx.x & (NRANGE - 1);
    const int c = blockIdx.x >> 3;
    const int lo = r * B;
    const int* nodes = blockIdx.y ? dstArr : srcArr;
    unsigned* partial = blockIdx.y ? partial_d : partial_s;

    for (int b = threadIdx.x; b < B; b += 256) hist[b] = 0u;
    __syncthreads();

    const int beg = c * chunkE, end = min(beg + chunkE, E);
    const int n4 = (end - beg) >> 2;           // beg is 4-aligned (chunkE %4==0)
    const int4* p = (const int4*)(nodes + beg);
    for (int j = threadIdx.x; j < n4; j += 256) {
        int4 v = p[j];
        int a;
        a = v.x - lo; if ((unsigned)a < (unsigned)B) atomicAdd(&hist[a], 1u);
        a = v.y - lo; if ((unsigned)a < (unsigned)B) atomicAdd(&hist[a], 1u);
        a = v.z - lo; if ((unsigned)a < (unsigned)B) atomicAdd(&hist[a], 1u);
        a = v.w - lo; if ((unsigned)a < (unsigned)B) atomicAdd(&hist[a], 1u);
    }
    for (int j = beg + (n4 << 2) + threadIdx.x; j < end; j += 256) {
        int a = nodes[j] - lo;
        if ((unsigned)a < (unsigned)B) atomicAdd(&hist[a], 1u);
    }
    __syncthreads();
    unsigned* outp = partial + (size_t)(r * C + c) * B;
    for (int b = threadIdx.x; b < B; b += 256) outp[b] = hist[b];
}

// ---- per-node: sum partials -> norms/deg_d; partial_d -> exclusive prefix ----
__global__ __launch_bounds__(256) void k_reduce_norm(const unsigned* __restrict__ partial_s,
                                                     unsigned* __restrict__ partial_d,
                                                     float* __restrict__ norm_s,
                                                     float* __restrict__ norm_d,
                                                     unsigned* __restrict__ deg_d,
                                                     int N, int B, int C) {
    int i = blockIdx.x * 256 + threadIdx.x;
    if (i >= N) return;
    int r = i / B, b = i - r * B;
    size_t base = (size_t)r * C * B + b;
    unsigned ds = 0;
    for (int c = 0; c < C; ++c) ds += partial_s[base + (size_t)c * B];
    unsigned dd = 0;
    for (int c = 0; c < C; ++c) {
        size_t ix = base + (size_t)c * B;
        unsigned v = partial_d[ix];
        partial_d[ix] = dd;                    // exclusive prefix over chunks
        dd += v;
    }
    deg_d[i] = dd;
    norm_s[i] = ds ? rsqrtf((float)ds) : 0.0f;
    norm_d[i] = dd ? rsqrtf((float)dd) : 0.0f;
}

// w2l[c] = sum_j W2[c][j]*Wl[j]; c0 = b2.Wl + bl
__global__ void k_w2l(const float* __restrict__ W2, const float* __restrict__ b2,
                      const float* __restrict__ Wl, const float* __restrict__ bl,
                      float* __restrict__ w2l, float* __restrict__ c0) {
    int c = threadIdx.x; // 64 threads
    float acc = 0.f;
#pragma unroll
    for (int j = 0; j < 32; ++j) acc += W2[c * 32 + j] * Wl[j];
    w2l[c] = acc;
    if (c == 0) {
        float s = 0.f;
#pragma unroll
        for (int j = 0; j < 32; ++j) s += b2[j] * Wl[j];
        *c0 = s + bl[0];
    }
}

// ---- W1 [128][64] fp32 -> wt [64][128] fp16 (transposed), once ----
__global__ __launch_bounds__(256) void k_wt(const float* __restrict__ W1,
                                            _Float16* __restrict__ wt) {
    int t = threadIdx.x;
    for (int i = 0; i < 32; ++i) {
        int e = i * 256 + t;       // 8192 elements
        int k = e >> 6, n = e & 63;
        wt[n * 128 + k] = (_Float16)W1[e];
    }
}

// ---- scan: deg_d -> exclusive offsets (N+1) ----
__global__ __launch_bounds__(256) void k_blocksum(const unsigned* __restrict__ deg,
                                                  unsigned* __restrict__ partial, int N) {
    __shared__ unsigned sw[4];
    int i = blockIdx.x * 256 + threadIdx.x;
    unsigned v = (i < N) ? deg[i] : 0u;
#pragma unroll
    for (int off = 32; off; off >>= 1) v += __shfl_xor((int)v, off);
    if ((threadIdx.x & 63) == 0) sw[threadIdx.x >> 6] = v;
    __syncthreads();
    if (threadIdx.x == 0) partial[blockIdx.x] = sw[0] + sw[1] + sw[2] + sw[3];
}

__global__ __launch_bounds__(512) void k_scanpartial(const unsigned* __restrict__ partial,
                                                     unsigned* __restrict__ blockoff,
                                                     unsigned* __restrict__ offsets,
                                                     int nb, int N) {
    __shared__ unsigned s[512];
    int t = threadIdx.x;
    unsigned v = (t < nb) ? partial[t] : 0u;
    s[t] = v;
    __syncthreads();
    for (int off = 1; off < 512; off <<= 1) {
        unsigned a = (t >= off) ? s[t - off] : 0u;
        __syncthreads();
        s[t] += a;
        __syncthreads();
    }
    if (t < nb) blockoff[t] = s[t] - v;       // exclusive
    if (t == nb - 1) offsets[N] = s[t];       // total = E
}

__global__ __launch_bounds__(256) void k_offsets(const unsigned* __restrict__ deg,
                                                 const unsigned* __restrict__ blockoff,
                                                 unsigned* __restrict__ offsets, int N) {
    __shared__ unsigned s[256];
    int t = threadIdx.x;
    int i = blockIdx.x * 256 + t;
    unsigned v = (i < N) ? deg[i] : 0u;
    s[t] = v;
    __syncthreads();
    for (int off = 1; off < 256; off <<= 1) {
        unsigned a = (t >= off) ? s[t - off] : 0u;
        __syncthreads();
        s[t] += a;
        __syncthreads();
    }
    if (i < N) offsets[i] = blockoff[blockIdx.x] + s[t] - v;
}

// ---- fill: LDS cursors seeded from offsets + chunk-prefix; LDS atomics only ----
__global__ __launch_bounds__(256) void k_fill(const int* __restrict__ src,
                                              const int* __restrict__ dst,
                                              const unsigned* __restrict__ offsets,
                                              const unsigned* __restrict__ rel,
                                              unsigned* __restrict__ csr,
                                              int N, int E, int B, int C, int chunkE) {
    extern __shared__ unsigned curs[];
    const int r = blockIdx.x & (NRANGE - 1);
    const int c = blockIdx.x >> 3;
    const int lo = r * B;
    const int bins = min(B, N - lo);
    const unsigned* relp = rel + (size_t)(r * C + c) * B;
    for (int b = threadIdx.x; b < bins; b += 256)
        curs[b] = offsets[lo + b] + relp[b];
    __syncthreads();

    const int beg = c * chunkE, end = min(beg + chunkE, E);
    const int n4 = (end - beg) >> 2;
    const int4* pd = (const int4*)(dst + beg);
    const int4* ps = (const int4*)(src + beg);
    for (int j = threadIdx.x; j < n4; j += 256) {
        int4 d4 = pd[j];
        int4 s4 = ps[j];
        int a;
        a = d4.x - lo; if ((unsigned)a < (unsigned)bins) csr[atomicAdd(&curs[a], 1u)] = (unsigned)s4.x;
        a = d4.y - lo; if ((unsigned)a < (unsigned)bins) csr[atomicAdd(&curs[a], 1u)] = (unsigned)s4.y;
        a = d4.z - lo; if ((unsigned)a < (unsigned)bins) csr[atomicAdd(&curs[a], 1u)] = (unsigned)s4.z;
        a = d4.w - lo; if ((unsigned)a < (unsigned)bins) csr[atomicAdd(&curs[a], 1u)] = (unsigned)s4.w;
    }
    for (int j = beg + (n4 << 2) + threadIdx.x; j < end; j += 256) {
        int a = dst[j] - lo;
        if ((unsigned)a < (unsigned)bins) csr[atomicAdd(&curs[a], 1u)] = (unsigned)src[j];
    }
}

// h1h = fp16( (x * ns[:,None]) @ W1 )  via MFMA 16x16x32_f16.
// Block: 4 waves x 16 rows = 64 rows; cols 64 = 4 n-tiles; K=128 = 4 k-steps.
// B-frags (W) in VGPRs; A from LDS-staged fp16 x tile (XOR-swizzled).
__global__ __launch_bounds__(256) void k_gemm1(const float* __restrict__ x,
                                               const _Float16* __restrict__ wt,
                                               const float* __restrict__ norm_s,
                                               __half* __restrict__ h1h, int N) {
    __shared__ __align__(16) _Float16 xs[64 * 128];
    const int tid = threadIdx.x, lane = tid & 63, wv = tid >> 6;
    const int r0 = blockIdx.x * 64;

    // B fragments: col = nt*16 + (lane&15), k = kt*32 + (lane>>4)*8 + b
    f16x8 bf[4][4];
#pragma unroll
    for (int kt = 0; kt < 4; ++kt)
#pragma unroll
        for (int nt = 0; nt < 4; ++nt)
            bf[kt][nt] = *(const f16x8*)&wt[(nt * 16 + (lane & 15)) * 128 +
                                            kt * 32 + (lane >> 4) * 8];

    // stage x tile -> fp16 LDS, swizzled (byte ^= (r&7)<<4)
#pragma unroll
    for (int it = 0; it < 8; ++it) {
        int e = it * 256 + tid;              // float4 index, 2048 total
        int r = e >> 5, c = e & 31;          // row, float4-within-row
        int row = r0 + r;
        float4 v = (row < N) ? ((const float4*)x)[(size_t)row * 32 + c]
                             : make_float4(0.f, 0.f, 0.f, 0.f);
        __half2 lo2 = __floats2half2_rn(v.x, v.y);
        __half2 hi2 = __floats2half2_rn(v.z, v.w);
        uint2 pk;
        pk.x = *(unsigned*)&lo2;
        pk.y = *(unsigned*)&hi2;
        int byte = r * 256 + c * 8;
        byte ^= (r & 7) << 4;
        *(uint2*)((char*)xs + byte) = pk;
    }
    __syncthreads();

    f32x4 acc[4] = {};
    const int rloc = wv * 16 + (lane & 15);   // A row within block tile
#pragma unroll
    for (int kt = 0; kt < 4; ++kt) {
        int byte = rloc * 256 + (kt * 32 + (lane >> 4) * 8) * 2;
        byte ^= (rloc & 7) << 4;
        f16x8 af = *(const f16x8*)((char*)xs + byte);
#pragma unroll
        for (int nt = 0; nt < 4; ++nt)
            acc[nt] = __builtin_amdgcn_mfma_f32_16x16x32_f16(af, bf[kt][nt], acc[nt], 0, 0, 0);
    }

    // D: col = nt*16 + (lane&15), row = wv*16 + (lane>>4)*4 + j
#pragma unroll
    for (int j = 0; j < 4; ++j) {
        int row = r0 + wv * 16 + (lane >> 4) * 4 + j;
        if (row < N) {
            float ns = norm_s[row];
#pragma unroll
            for (int nt = 0; nt < 4; ++nt)
                h1h[(size_t)row * 64 + nt * 16 + (lane & 15)] =
                    __float2half(acc[nt][j] * ns);
        }
    }
}

// One wave per node. Two edges per step: lanes 0-31 = even slot, 32-63 = odd.
// Each lane loads __half2 (2 channels) -> 256B/instruction, 8 edges in flight.
__global__ __launch_bounds__(256) void k_agg_rdot(const unsigned* __restrict__ offsets,
                                                  const unsigned* __restrict__ csr,
                                                  const __half* __restrict__ h1h,
                                                  const float* __restrict__ norm_s,
                                                  const float* __restrict__ norm_d,
                                                  const float* __restrict__ b1,
                                                  const float* __restrict__ w2l,
                                                  float* __restrict__ s_node, int N) {
    const int lane = threadIdx.x & 63;
    const int slot = lane >> 5;    // which edge of the pair
    const int p = lane & 31;       // channel pair -> channels 2p, 2p+1
    const int v = (blockIdx.x * 256 + threadIdx.x) >> 6;
    if (v >= N) return;
    const unsigned beg = offsets[v], end = offsets[v + 1];

    float ax = 0.f, ay = 0.f;
    for (unsigned base = beg; base < end; base += WAVE) {
        const int n = (int)min((unsigned)WAVE, end - base);
        int sv = (lane < n) ? (int)csr[base + lane] : 0;
        int i = 0;
        for (; i + 8 <= n; i += 8) {   // 4 independent 256B gathers in flight
            int s0 = __shfl(sv, i + 0 + slot);
            int s1 = __shfl(sv, i + 2 + slot);
            int s2 = __shfl(sv, i + 4 + slot);
            int s3 = __shfl(sv, i + 6 + slot);
            unsigned u0 = *(const unsigned*)&h1h[(size_t)s0 * 64 + 2 * p];
            unsigned u1 = *(const unsigned*)&h1h[(size_t)s1 * 64 + 2 * p];
            unsigned u2 = *(const unsigned*)&h1h[(size_t)s2 * 64 + 2 * p];
            unsigned u3 = *(const unsigned*)&h1h[(size_t)s3 * 64 + 2 * p];
            float2 f0 = __half22float2(*(__half2*)&u0);
            float2 f1 = __half22float2(*(__half2*)&u1);
            float2 f2 = __half22float2(*(__half2*)&u2);
            float2 f3 = __half22float2(*(__half2*)&u3);
            ax += (f0.x + f1.x) + (f2.x + f3.x);
            ay += (f0.y + f1.y) + (f2.y + f3.y);
        }
        for (; i < n; i += 2) {
            int e = i + slot;
            int s = __shfl(sv, min(e, n - 1));
            if (e < n) {
                unsigned u = *(const unsigned*)&h1h[(size_t)s * 64 + 2 * p];
                float2 f = __half22float2(*(__half2*)&u);
                ax += f.x; ay += f.y;
            }
        }
    }
    // merge the two edge-slots: lanes l and l^32 hold the same channel pair
    ax += __shfl_xor(ax, 32);
    ay += __shfl_xor(ay, 32);

    float nd = norm_d[v];
    float t = fmaxf(fmaf(ax, nd, b1[2 * p]), 0.f) * w2l[2 * p]
            + fmaxf(fmaf(ay, nd, b1[2 * p + 1]), 0.f) * w2l[2 * p + 1];
#pragma unroll
    for (int off = 16; off; off >>= 1) t += __shfl_xor(t, off);
    if (lane == 0) s_node[v] = t * norm_s[v];
}

// out[v] = nd[v] * sum_{in-edges} s_node[src] + c0
__global__ __launch_bounds__(256) void k_out(const unsigned* __restrict__ offsets,
                                             const unsigned* __restrict__ csr,
                                             const float* __restrict__ s_node,
                                             const float* __restrict__ norm_d,
                                             const float* __restrict__ c0,
                                             float* __restrict__ out, int N) {
    int v = blockIdx.x * 256 + threadIdx.x;
    if (v >= N) return;
    unsigned beg = offsets[v], end = offsets[v + 1];
    float sum = 0.f;
    unsigned j = beg;
    for (; j + 4 <= end; j += 4) {
        float a = s_node[csr[j + 0]], b = s_node[csr[j + 1]];
        float c = s_node[csr[j + 2]], d = s_node[csr[j + 3]];
        sum += a + b + c + d;
    }
    for (; j < end; ++j) sum += s_node[csr[j]];
    out[v] = fmaf(sum, norm_d[v], *c0);
}

extern "C" void kernel_launch(void* const* d_in, const int* in_sizes, int n_in,
                              void* d_out, int out_size, void* d_ws, size_t ws_size,
                              hipStream_t stream) {
    const float* x  = (const float*)d_in[0];
    const int*   ei = (const int*)d_in[1];
    const float* W1 = (const float*)d_in[2];
    const float* b1 = (const float*)d_in[3];
    const float* W2 = (const float*)d_in[4];
    const float* b2 = (const float*)d_in[5];
    const float* Wl = (const float*)d_in[6];
    const float* bl = (const float*)d_in[7];

    const int N = in_sizes[0] / 128;
    const int E = in_sizes[1] / 2;
    const int* src = ei;
    const int* dst = ei + E;
    const int NB = (N + 255) / 256;
    const int B = (N + NRANGE - 1) / NRANGE;       // bins per range

    // pick chunk count C so partials fit the workspace
    size_t baseBytes = 0;
    {
        auto pad = [](size_t b) { return (b + 255) & ~(size_t)255; };
        baseBytes = pad((size_t)N * 4) * 3 + pad((size_t)(N + 1) * 4) +
                    pad((size_t)NB * 4) * 2 + pad((size_t)N * 64 * 2) +
                    pad((size_t)E * 4) + pad((size_t)N * 4) + pad(64 * 4) + pad(4) +
                    pad(64 * 128 * 2);
    }
    int C = 32;
    while (C > 4 && baseBytes + 2ull * NRANGE * C * B * 4ull > ws_size) C >>= 1;
    const int chunkE = (((E + C - 1) / C) + 3) & ~3;

    char* w = (char*)d_ws;
    auto alloc = [&](size_t bytes) -> void* {
        void* r = (void*)w;
        w += (bytes + 255) & ~(size_t)255;
        return r;
    };
    float*    norm_s    = (float*)alloc((size_t)N * 4);
    float*    norm_d    = (float*)alloc((size_t)N * 4);
    unsigned* deg_d     = (unsigned*)alloc((size_t)N * 4);
    unsigned* offsets   = (unsigned*)alloc((size_t)(N + 1) * 4);
    unsigned* partial   = (unsigned*)alloc((size_t)NB * 4);
    unsigned* blockoff  = (unsigned*)alloc((size_t)NB * 4);
    __half*   h1h       = (__half*)alloc((size_t)N * 64 * 2);
    unsigned* csr       = (unsigned*)alloc((size_t)E * 4);
    float*    s_node    = (float*)alloc((size_t)N * 4);
    float*    w2l       = (float*)alloc(64 * 4);
    float*    c0        = (float*)alloc(4);
    _Float16* wt        = (_Float16*)alloc(64 * 128 * 2);
    unsigned* partial_s = (unsigned*)alloc((size_t)NRANGE * C * B * 4);
    unsigned* partial_d = (unsigned*)alloc((size_t)NRANGE * C * B * 4);

    float* out = (float*)d_out;
    const size_t ldsB = (size_t)B * 4;

    k_hist<<<dim3(NRANGE * C, 2), 256, ldsB, stream>>>(src, dst, partial_s, partial_d,
                                                       E, B, C, chunkE);
    k_w2l<<<1, 64, 0, stream>>>(W2, b2, Wl, bl, w2l, c0);
    k_wt<<<1, 256, 0, stream>>>(W1, wt);
    k_reduce_norm<<<NB, 256, 0, stream>>>(partial_s, partial_d, norm_s, norm_d,
                                          deg_d, N, B, C);

    k_blocksum<<<NB, 256, 0, stream>>>(deg_d, partial, N);
    k_scanpartial<<<1, 512, 0, stream>>>(partial, blockoff, offsets, NB, N);
    k_offsets<<<NB, 256, 0, stream>>>(deg_d, blockoff, offsets, N);

    k_fill<<<NRANGE * C, 256, ldsB, stream>>>(src, dst, offsets, partial_d, csr,
                                              N, E, B, C, chunkE);

    k_gemm1<<<(N + 63) / 64, 256, 0, stream>>>(x, wt, norm_s, h1h, N);

    k_agg_rdot<<<(N + 3) / 4, 256, 0, stream>>>(offsets, csr, h1h, norm_s, norm_d,
                                                b1, w2l, s_node, N);
    k_out<<<NB, 256, 0, stream>>>(offsets, csr, s_node, norm_d, c0, out, N);
}